// Round 5
// baseline (352.411 us; speedup 1.0000x reference)
//
#include <hip/hip_runtime.h>

typedef unsigned short u16;
typedef unsigned int u32;
typedef unsigned long long u64;

#define N_NODES 100000
#define N_EDGES 600000
#define D 128
#define NPG 1000
#define NGRAPH 100
#define MBW 3136          // mask words (padded) >= ceil(100000/32)

#define CAP_SLOTS 65536   // CSR slots (expected ~29.4k)
#define CAP_L1    16384   // S1 nodes (expected ~4.9k)
#define CAP_L2    4096    // S2 nodes (expected ~700)
#define CAP_E2    16384   // edges into S2 (expected ~4.2k)
#define CAP_E3    4096    // edges into masters (expected ~600)

#define C_SLOT 0
#define C_L1   1
#define C_L2   2
#define C_E2   3
#define C_E3   4

__device__ __forceinline__ float bf2f(u16 u) {
  return __uint_as_float(((u32)u) << 16);
}
__device__ __forceinline__ u16 f2bf(float f) {
  u32 u = __float_as_uint(f);
  u32 r = (u + 0x7FFFu + ((u >> 16) & 1u)) >> 16;  // RNE
  return (u16)r;
}
__device__ __forceinline__ void fma4(float4& acc, float a, const float4 w) {
  acc.x = fmaf(a, w.x, acc.x);
  acc.y = fmaf(a, w.y, acc.y);
  acc.z = fmaf(a, w.z, acc.z);
  acc.w = fmaf(a, w.w, acc.w);
}
__device__ __forceinline__ float4 bf4(uint2 u) {
  return make_float4(bf2f((u16)(u.x & 0xFFFFu)), bf2f((u16)(u.x >> 16)),
                     bf2f((u16)(u.y & 0xFFFFu)), bf2f((u16)(u.y >> 16)));
}
__device__ __forceinline__ void add4(float4& a, const float4 b) {
  a.x += b.x; a.y += b.y; a.z += b.z; a.w += b.w;
}
__device__ __forceinline__ float4 shfl4(float4 v, int lane) {
  return make_float4(__shfl(v.x, lane, 32), __shfl(v.y, lane, 32),
                     __shfl(v.z, lane, 32), __shfl(v.w, lane, 32));
}
__device__ __forceinline__ int mbit(const u32* __restrict__ mb, int n) {
  return (mb[n >> 5] >> (n & 31)) & 1u;
}
__device__ __forceinline__ void mset(u32* __restrict__ mb, int n) {
  atomicOr(&mb[n >> 5], 1u << (n & 31));
}

// ---------------- cone construction ----------------
// invariant: mb1 >= mb2 maintained at every write (no OR pass needed)

// masters + src of edges into masters -> mb2 (and mb1)
__global__ __launch_bounds__(256) void k_scan3(const int4* __restrict__ src4,
                                               const int4* __restrict__ dst4,
                                               u32* __restrict__ mb1,
                                               u32* __restrict__ mb2) {
  int i = blockIdx.x * 256 + threadIdx.x;
  if (blockIdx.x == 0 && threadIdx.x < NGRAPH) {
    mset(mb2, threadIdx.x * NPG);
    mset(mb1, threadIdx.x * NPG);
  }
  if (i >= N_EDGES / 4) return;
  int4 d = dst4[i], s = src4[i];
  if (d.x % NPG == 0) { mset(mb2, s.x); mset(mb1, s.x); }
  if (d.y % NPG == 0) { mset(mb2, s.y); mset(mb1, s.y); }
  if (d.z % NPG == 0) { mset(mb2, s.z); mset(mb1, s.z); }
  if (d.w % NPG == 0) { mset(mb2, s.w); mset(mb1, s.w); }
}

// mb1 |= src of edges into S2
__global__ __launch_bounds__(256) void k_scan2(const int4* __restrict__ src4,
                                               const int4* __restrict__ dst4,
                                               const u32* __restrict__ mb2,
                                               u32* __restrict__ mb1) {
  int i = blockIdx.x * 256 + threadIdx.x;
  if (i >= N_EDGES / 4) return;
  int4 d = dst4[i], s = src4[i];
  if (mbit(mb2, d.x)) mset(mb1, s.x);
  if (mbit(mb2, d.y)) mset(mb1, s.y);
  if (mbit(mb2, d.z)) mset(mb1, s.z);
  if (mbit(mb2, d.w)) mset(mb1, s.w);
}

// deg[d]++ for edges with dst in S1
__global__ __launch_bounds__(256) void k_scan1(const int4* __restrict__ dst4,
                                               const u32* __restrict__ mb1,
                                               int* __restrict__ deg) {
  int i = blockIdx.x * 256 + threadIdx.x;
  if (i >= N_EDGES / 4) return;
  int4 d = dst4[i];
  if (mbit(mb1, d.x)) atomicAdd(&deg[d.x], 1);
  if (mbit(mb1, d.y)) atomicAdd(&deg[d.y], 1);
  if (mbit(mb1, d.z)) atomicAdd(&deg[d.z], 1);
  if (mbit(mb1, d.w)) atomicAdd(&deg[d.w], 1);
}

// CSR segment allocation (wave prefix-scan, 1 atomic/wave) + L1/L2 lists
__global__ __launch_bounds__(256) void k_alloc(const u32* __restrict__ mb1,
                                               const u32* __restrict__ mb2,
                                               const int* __restrict__ deg,
                                               int* __restrict__ offn,
                                               int* __restrict__ cur,
                                               int* __restrict__ L1,
                                               int* __restrict__ L2,
                                               int* __restrict__ ctrl) {
  int t = blockIdx.x * 256 + threadIdx.x;
  int lane = threadIdx.x & 63;
  bool inb = t < N_NODES;
  bool mk1 = inb && mbit(mb1, t);
  bool mk2 = inb && mbit(mb2, t);

  int v = mk1 ? deg[t] : 0;
  int incl = v;
#pragma unroll
  for (int o = 1; o < 64; o <<= 1) {
    int u = __shfl_up(incl, o, 64);
    if (lane >= o) incl += u;
  }
  int total = __shfl(incl, 63, 64);
  int sbase = 0;
  if (lane == 0 && total > 0) sbase = atomicAdd(&ctrl[C_SLOT], total);
  sbase = __shfl(sbase, 0, 64);
  int myoff = sbase + incl - v;
  if (mk1) { offn[t] = myoff; cur[t] = myoff; }

  u64 bal = __ballot(mk1);
  int pos = __popcll(bal & ((1ull << lane) - 1ull));
  int lbase = 0;
  if (lane == 0 && bal) lbase = atomicAdd(&ctrl[C_L1], __popcll(bal));
  lbase = __shfl(lbase, 0, 64);
  if (mk1 && lbase + pos < CAP_L1) L1[lbase + pos] = t;

  u64 bal2 = __ballot(mk2);
  int pos2 = __popcll(bal2 & ((1ull << lane) - 1ull));
  int lbase2 = 0;
  if (lane == 0 && bal2) lbase2 = atomicAdd(&ctrl[C_L2], __popcll(bal2));
  lbase2 = __shfl(lbase2, 0, 64);
  if (mk2 && lbase2 + pos2 < CAP_L2) L2[lbase2 + pos2] = t;
}

// scatter edges into CSR; emit E2/E3 packed {p, src, dst, e}
__global__ __launch_bounds__(256) void k_scatter(const int4* __restrict__ src4,
                                                 const int4* __restrict__ dst4,
                                                 const u32* __restrict__ mb1,
                                                 const u32* __restrict__ mb2,
                                                 int* __restrict__ cur,
                                                 int* __restrict__ csr_src,
                                                 int* __restrict__ csr_eid,
                                                 int4* __restrict__ E2,
                                                 int4* __restrict__ E3,
                                                 int* __restrict__ ctrl) {
  int i = blockIdx.x * 256 + threadIdx.x;
  if (i >= N_EDGES / 4) return;
  int4 dv = dst4[i], sv = src4[i];
  int ds[4] = {dv.x, dv.y, dv.z, dv.w};
  int ss[4] = {sv.x, sv.y, sv.z, sv.w};
#pragma unroll
  for (int j = 0; j < 4; ++j) {
    int d = ds[j];
    if (!mbit(mb1, d)) continue;
    int s = ss[j], e = i * 4 + j;
    int p = atomicAdd(&cur[d], 1);
    if (p < CAP_SLOTS) { csr_src[p] = s; csr_eid[p] = e; }
    if (mbit(mb2, d)) {
      int a = atomicAdd(&ctrl[C_E2], 1);
      if (a < CAP_E2) E2[a] = make_int4(p, s, d, e);
    }
    if (d % NPG == 0) {
      int b = atomicAdd(&ctrl[C_E3], 1);
      if (b < CAP_E3) E3[b] = make_int4(p, s, d, e);
    }
  }
}

// concat [ws;wm] -> contiguous [384][128] for the 3 node-layer GEMMs
__global__ __launch_bounds__(256) void k_wcat(const float* __restrict__ ws1, const float* __restrict__ wm1,
                                              const float* __restrict__ ws2, const float* __restrict__ wm2,
                                              const float* __restrict__ ws3, const float* __restrict__ wm3,
                                              float* __restrict__ w1, float* __restrict__ w2,
                                              float* __restrict__ w3) {
  int t = blockIdx.x * 256 + threadIdx.x;
  if (t >= 384 * D) return;
  float v1, v2, v3;
  if (t < 128 * D) { v1 = ws1[t]; v2 = ws2[t]; v3 = ws3[t]; }
  else { int u = t - 128 * D; v1 = wm1[u]; v2 = wm2[u]; v3 = wm3[u]; }
  w1[t] = v1; w2[t] = v2; w3[t] = v3;
}

// ---------------- gathers: build dense A rows [x | sx | se] (K=384) ----------------

// node gather. layer1: tok!=0 -> x rows from emb[tok[.]], se = (Σattr)@wproj + deg*bproj
//              layer2/3: x rows from xin, se = Σ bf16 ea.  L==0 -> masters (i*NPG), n_=NGRAPH
__global__ __launch_bounds__(256) void k_gat_node(const int* __restrict__ tok,
                                                  const float* __restrict__ emb,
                                                  const float* __restrict__ xin,
                                                  const float* __restrict__ attr,
                                                  const float* __restrict__ wproj,
                                                  const float* __restrict__ bproj,
                                                  const u16* __restrict__ ea,
                                                  const int* __restrict__ csr_src,
                                                  const int* __restrict__ csr_eid,
                                                  const int* __restrict__ offn,
                                                  const int* __restrict__ cur,
                                                  const int* __restrict__ L,
                                                  const int* __restrict__ ctrl, int slot, int cap,
                                                  float* __restrict__ A,
                                                  float* __restrict__ degf) {
  int n_ = L ? ctrl[slot] : NGRAPH;
  if (n_ > cap) n_ = cap;
  int sub = threadIdx.x >> 5, q = threadIdx.x & 31;
  for (int i = blockIdx.x * 8 + sub; i < n_; i += gridDim.x * 8) {
    int n = L ? L[i] : i * NPG;
    int o = offn[n], end = cur[n];
    float dgf = (float)(end - o);
    float4 sx = make_float4(0.f, 0.f, 0.f, 0.f);
    float4 se = make_float4(0.f, 0.f, 0.f, 0.f);
    float4 xn;
    if (tok) {
      float4 sa = make_float4(0.f, 0.f, 0.f, 0.f);
      for (int p = o; p < end; ++p) {
        int s = csr_src[p], e = csr_eid[p];
        add4(sx, ((const float4*)(emb + (size_t)tok[s] * D))[q]);
        add4(sa, ((const float4*)(attr + (size_t)e * 16))[q & 3]);
      }
      float4 bp = ((const float4*)bproj)[q];
      se = make_float4(bp.x * dgf, bp.y * dgf, bp.z * dgf, bp.w * dgf);
      const float4* wp = (const float4*)wproj;
#pragma unroll
      for (int k4 = 0; k4 < 4; ++k4) {
        float4 xv = shfl4(sa, k4);
        fma4(se, xv.x, wp[(k4 * 4 + 0) * 32 + q]);
        fma4(se, xv.y, wp[(k4 * 4 + 1) * 32 + q]);
        fma4(se, xv.z, wp[(k4 * 4 + 2) * 32 + q]);
        fma4(se, xv.w, wp[(k4 * 4 + 3) * 32 + q]);
      }
      xn = ((const float4*)(emb + (size_t)tok[n] * D))[q];
    } else {
      for (int p = o; p < end; ++p) {
        int s = csr_src[p];
        add4(sx, ((const float4*)(xin + (size_t)s * D))[q]);
        add4(se, bf4(((const uint2*)(ea + (size_t)p * D))[q]));
      }
      xn = ((const float4*)(xin + (size_t)n * D))[q];
    }
    float4* Ar = (float4*)(A + (size_t)i * 384);
    Ar[q] = xn;
    Ar[32 + q] = sx;
    Ar[64 + q] = se;
    if (q == 0) degf[i] = dgf;
  }
}

// edge gather: A row = [x_dst | x_src | ev]; layer1 ev = attr@wproj+bproj, layer2 ev = bf16 ea[p]
__global__ __launch_bounds__(256) void k_gat_edge(const int* __restrict__ tok,
                                                  const float* __restrict__ emb,
                                                  const float* __restrict__ xin,
                                                  const float* __restrict__ attr,
                                                  const float* __restrict__ wproj,
                                                  const float* __restrict__ bproj,
                                                  const u16* __restrict__ ea,
                                                  const int4* __restrict__ EL,
                                                  const int* __restrict__ ctrl, int slot, int cap,
                                                  float* __restrict__ A) {
  int n_ = ctrl[slot];
  if (n_ > cap) n_ = cap;
  int sub = threadIdx.x >> 5, q = threadIdx.x & 31;
  for (int i = blockIdx.x * 8 + sub; i < n_; i += gridDim.x * 8) {
    int4 t = EL[i];
    int p = t.x, s = t.y, d = t.z, e = t.w;
    float4 xd, xs, ev;
    if (tok) {
      xd = ((const float4*)(emb + (size_t)tok[d] * D))[q];
      xs = ((const float4*)(emb + (size_t)tok[s] * D))[q];
      float4 av = ((const float4*)(attr + (size_t)e * 16))[q & 3];
      ev = ((const float4*)bproj)[q];
      const float4* wp = (const float4*)wproj;
#pragma unroll
      for (int k4 = 0; k4 < 4; ++k4) {
        float4 xv = shfl4(av, k4);
        fma4(ev, xv.x, wp[(k4 * 4 + 0) * 32 + q]);
        fma4(ev, xv.y, wp[(k4 * 4 + 1) * 32 + q]);
        fma4(ev, xv.z, wp[(k4 * 4 + 2) * 32 + q]);
        fma4(ev, xv.w, wp[(k4 * 4 + 3) * 32 + q]);
      }
    } else {
      xd = ((const float4*)(xin + (size_t)d * D))[q];
      xs = ((const float4*)(xin + (size_t)s * D))[q];
      ev = bf4(((const uint2*)(ea + (size_t)p * D))[q]);
    }
    float4* Ar = (float4*)(A + (size_t)i * 384);
    Ar[q] = xd;
    Ar[32 + q] = xs;
    Ar[64 + q] = ev;
  }
}

// ---------------- register-tiled GEMM: C[M][128] = A[M][384] @ W + epilogue ----------------
// each 32-lane group computes 4 rows -> 4x weight reuse; lane q owns cols 4q..4q+3
__global__ __launch_bounds__(256) void k_gemm(const float* __restrict__ A,
                                              const float* __restrict__ W,
                                              const float* __restrict__ bias,
                                              const float* __restrict__ bm,
                                              const float* __restrict__ degf,
                                              const int* __restrict__ L,
                                              const int4* __restrict__ EL,
                                              float* __restrict__ outf,
                                              u16* __restrict__ outb,
                                              const int* __restrict__ ctrl, int slot, int cap,
                                              int relu) {
  int M = (slot < 0) ? NGRAPH : ctrl[slot];
  if (M > cap) M = cap;
  int sub = threadIdx.x >> 5, q = threadIdx.x & 31;
  const float4* W4 = (const float4*)W;
  float4 bias4 = ((const float4*)bias)[q];
  for (int r0 = (blockIdx.x * 8 + sub) * 4; r0 < M; r0 += gridDim.x * 8 * 4) {
    float4 af[4][3];
#pragma unroll
    for (int r = 0; r < 4; ++r) {
      int row = r0 + r;
      if (row > M - 1) row = M - 1;
      const float4* Ar = (const float4*)(A + (size_t)row * 384);
      af[r][0] = Ar[q];
      af[r][1] = Ar[32 + q];
      af[r][2] = Ar[64 + q];
    }
    float4 acc[4] = {bias4, bias4, bias4, bias4};
#pragma unroll
    for (int seg = 0; seg < 3; ++seg) {
#pragma unroll 4
      for (int k4 = 0; k4 < 32; ++k4) {
        float4 w0 = W4[(seg * 128 + k4 * 4 + 0) * 32 + q];
        float4 w1 = W4[(seg * 128 + k4 * 4 + 1) * 32 + q];
        float4 w2 = W4[(seg * 128 + k4 * 4 + 2) * 32 + q];
        float4 w3 = W4[(seg * 128 + k4 * 4 + 3) * 32 + q];
#pragma unroll
        for (int r = 0; r < 4; ++r) {
          float4 xv = shfl4(af[r][seg], k4);
          fma4(acc[r], xv.x, w0);
          fma4(acc[r], xv.y, w1);
          fma4(acc[r], xv.z, w2);
          fma4(acc[r], xv.w, w3);
        }
      }
    }
#pragma unroll
    for (int r = 0; r < 4; ++r) {
      int row = r0 + r;
      if (row < M) {
        float4 a = acc[r];
        if (degf) {
          float dg = degf[row];
          float4 bm4 = ((const float4*)bm)[q];
          a.x = fmaf(dg, bm4.x, a.x);
          a.y = fmaf(dg, bm4.y, a.y);
          a.z = fmaf(dg, bm4.z, a.z);
          a.w = fmaf(dg, bm4.w, a.w);
        }
        if (relu) {
          a.x = fmaxf(a.x, 0.f);
          a.y = fmaxf(a.y, 0.f);
          a.z = fmaxf(a.z, 0.f);
          a.w = fmaxf(a.w, 0.f);
        }
        if (outb) {
          int p = EL[row].x;
          u32 p0 = (u32)f2bf(a.x) | ((u32)f2bf(a.y) << 16);
          u32 p1 = (u32)f2bf(a.z) | ((u32)f2bf(a.w) << 16);
          ((uint2*)(outb + (size_t)p * D))[q] = make_uint2(p0, p1);
        } else {
          int idx = L ? L[row] : row;
          ((float4*)(outf + (size_t)idx * D))[q] = a;
        }
      }
    }
  }
}

extern "C" void kernel_launch(void* const* d_in, const int* in_sizes, int n_in,
                              void* d_out, int out_size, void* d_ws, size_t ws_size,
                              hipStream_t stream) {
  const int* tok = (const int*)d_in[0];
  const int* eidx = (const int*)d_in[1];
  const int4* src4 = (const int4*)eidx;
  const int4* dst4 = (const int4*)(eidx + N_EDGES);
  const float* attr = (const float*)d_in[2];
  const float* emb = (const float*)d_in[4];
  const float* w_proj = (const float*)d_in[5];
  const float* b_proj = (const float*)d_in[6];
  const float *ws_[3], *bs_[3], *wm_[3], *bm_[3], *we_[3], *be_[3];
  for (int i = 0; i < 3; ++i) {
    ws_[i] = (const float*)d_in[7 + 6 * i];
    bs_[i] = (const float*)d_in[8 + 6 * i];
    wm_[i] = (const float*)d_in[9 + 6 * i];
    bm_[i] = (const float*)d_in[10 + 6 * i];
    we_[i] = (const float*)d_in[11 + 6 * i];
    be_[i] = (const float*)d_in[12 + 6 * i];
  }
  float* out = (float*)d_out;

  // ---- workspace ----
  char* base = (char*)d_ws;
  size_t o = 0;
  int* ctrl = (int*)(base + o); o += 256;
  u32* mb1 = (u32*)(base + o); o += MBW * 4;
  u32* mb2 = (u32*)(base + o); o += MBW * 4;
  int* deg = (int*)(base + o); o += (size_t)N_NODES * 4;
  size_t zero_bytes = o;  // ctrl + masks + deg start at 0 each call
  int* offn = (int*)(base + o); o += (size_t)N_NODES * 4;
  int* cur = (int*)(base + o); o += (size_t)N_NODES * 4;
  int* csr_src = (int*)(base + o); o += (size_t)CAP_SLOTS * 4;
  int* csr_eid = (int*)(base + o); o += (size_t)CAP_SLOTS * 4;
  o = (o + 15) & ~(size_t)15;
  int4* E2 = (int4*)(base + o); o += (size_t)CAP_E2 * 16;
  int4* E3 = (int4*)(base + o); o += (size_t)CAP_E3 * 16;
  int* L1 = (int*)(base + o); o += (size_t)CAP_L1 * 4;
  int* L2 = (int*)(base + o); o += (size_t)CAP_L2 * 4;
  float* degf = (float*)(base + o); o += (size_t)CAP_L1 * 4;
  float* w1c = (float*)(base + o); o += (size_t)384 * D * 4;
  float* w2c = (float*)(base + o); o += (size_t)384 * D * 4;
  float* w3c = (float*)(base + o); o += (size_t)384 * D * 4;
  o = (o + 511) & ~(size_t)511;
  float* A = (float*)(base + o); o += (size_t)CAP_L1 * 384 * 4;   // 25 MB
  float* x1 = (float*)(base + o); o += (size_t)N_NODES * D * 4;   // 51 MB
  float* x2 = (float*)(base + o); o += (size_t)N_NODES * D * 4;   // 51 MB
  u16* ea = (u16*)(base + o); o += (size_t)CAP_SLOTS * D * 2;     // 16 MB

  hipMemsetAsync(d_ws, 0, zero_bytes, stream);

  dim3 B(256);
  const int EG4 = (N_EDGES / 4 + 255) / 256;  // 586
  const int NG = (N_NODES + 255) / 256;       // 391

  // cone + CSR
  k_scan3<<<EG4, B, 0, stream>>>(src4, dst4, mb1, mb2);
  k_scan2<<<EG4, B, 0, stream>>>(src4, dst4, mb2, mb1);
  k_scan1<<<EG4, B, 0, stream>>>(dst4, mb1, deg);
  k_alloc<<<NG, B, 0, stream>>>(mb1, mb2, deg, offn, cur, L1, L2, ctrl);
  k_scatter<<<EG4, B, 0, stream>>>(src4, dst4, mb1, mb2, cur,
                                   csr_src, csr_eid, E2, E3, ctrl);
  k_wcat<<<192, B, 0, stream>>>(ws_[0], wm_[0], ws_[1], wm_[1], ws_[2], wm_[2],
                                w1c, w2c, w3c);

  // layer 1 node: A = [emb | Σemb | Σattr-proj] on L1 -> x1 (relu)
  k_gat_node<<<640, B, 0, stream>>>(tok, emb, nullptr, attr, w_proj, b_proj, ea,
                                    csr_src, csr_eid, offn, cur,
                                    L1, ctrl, C_L1, CAP_L1, A, degf);
  k_gemm<<<256, B, 0, stream>>>(A, w1c, bs_[0], bm_[0], degf, L1, nullptr,
                                x1, nullptr, ctrl, C_L1, CAP_L1, 1);
  // layer 1 edge: A = [emb_d | emb_s | attr-proj] on E2 -> ea (bf16, relu)
  k_gat_edge<<<640, B, 0, stream>>>(tok, emb, nullptr, attr, w_proj, b_proj, ea,
                                    E2, ctrl, C_E2, CAP_E2, A);
  k_gemm<<<256, B, 0, stream>>>(A, we_[0], be_[0], nullptr, nullptr, nullptr, E2,
                                nullptr, ea, ctrl, C_E2, CAP_E2, 1);

  // layer 2 node: on L2 -> x2 (relu)
  k_gat_node<<<96, B, 0, stream>>>(nullptr, nullptr, x1, nullptr, nullptr, nullptr, ea,
                                   csr_src, csr_eid, offn, cur,
                                   L2, ctrl, C_L2, CAP_L2, A, degf);
  k_gemm<<<32, B, 0, stream>>>(A, w2c, bs_[1], bm_[1], degf, L2, nullptr,
                               x2, nullptr, ctrl, C_L2, CAP_L2, 1);
  // layer 2 edge: on E3 -> ea (bf16, relu)
  k_gat_edge<<<96, B, 0, stream>>>(nullptr, nullptr, x1, nullptr, nullptr, nullptr, ea,
                                   E3, ctrl, C_E3, CAP_E3, A);
  k_gemm<<<32, B, 0, stream>>>(A, we_[1], be_[1], nullptr, nullptr, nullptr, E3,
                               nullptr, ea, ctrl, C_E3, CAP_E3, 1);

  // layer 3: masters only (L = null -> row i is graph i), no relu -> out
  k_gat_node<<<13, B, 0, stream>>>(nullptr, nullptr, x2, nullptr, nullptr, nullptr, ea,
                                   csr_src, csr_eid, offn, cur,
                                   nullptr, ctrl, -1, NGRAPH, A, degf);
  k_gemm<<<13, B, 0, stream>>>(A, w3c, bs_[2], bm_[2], degf, nullptr, nullptr,
                               out, nullptr, ctrl, -1, NGRAPH, 0);
}

// Round 6
// 225.552 us; speedup vs baseline: 1.5624x; 1.5624x over previous
//
#include <hip/hip_runtime.h>

typedef unsigned short u16;
typedef unsigned int u32;
typedef unsigned long long u64;

#define N_NODES 100000
#define N_EDGES 600000
#define D 128
#define NPG 1000
#define NGRAPH 100
#define MBW 3136          // mask words (padded) >= ceil(100000/32)

#define CAP_SLOTS 65536   // CSR slots (expected ~29.4k)
#define CAP_L1    16384   // S1 nodes (expected ~4.9k)
#define CAP_L2    4096    // S2 nodes (expected ~700)
#define CAP_E2    16384   // edges into S2 (expected ~4.2k)
#define CAP_E3    4096    // edges into masters (expected ~600)

#define C_SLOT 0
#define C_L1   1
#define C_L2   2
#define C_E2   3
#define C_E3   4

__device__ __forceinline__ float bf2f(u16 u) {
  return __uint_as_float(((u32)u) << 16);
}
__device__ __forceinline__ u16 f2bf(float f) {
  u32 u = __float_as_uint(f);
  u32 r = (u + 0x7FFFu + ((u >> 16) & 1u)) >> 16;  // RNE
  return (u16)r;
}
__device__ __forceinline__ void fma4(float4& acc, float a, const float4 w) {
  acc.x = fmaf(a, w.x, acc.x);
  acc.y = fmaf(a, w.y, acc.y);
  acc.z = fmaf(a, w.z, acc.z);
  acc.w = fmaf(a, w.w, acc.w);
}
__device__ __forceinline__ float4 bf4(uint2 u) {
  return make_float4(bf2f((u16)(u.x & 0xFFFFu)), bf2f((u16)(u.x >> 16)),
                     bf2f((u16)(u.y & 0xFFFFu)), bf2f((u16)(u.y >> 16)));
}
__device__ __forceinline__ void add4(float4& a, const float4 b) {
  a.x += b.x; a.y += b.y; a.z += b.z; a.w += b.w;
}
__device__ __forceinline__ float4 shfl4(float4 v, int lane) {
  return make_float4(__shfl(v.x, lane, 32), __shfl(v.y, lane, 32),
                     __shfl(v.z, lane, 32), __shfl(v.w, lane, 32));
}
__device__ __forceinline__ int mbit(const u32* __restrict__ mb, int n) {
  return (mb[n >> 5] >> (n & 31)) & 1u;
}
__device__ __forceinline__ void mset(u32* __restrict__ mb, int n) {
  atomicOr(&mb[n >> 5], 1u << (n & 31));
}

// ---------------- cone construction ----------------
// invariant: mb1 >= mb2 at every write

__global__ __launch_bounds__(256) void k_scan3(const int4* __restrict__ src4,
                                               const int4* __restrict__ dst4,
                                               u32* __restrict__ mb1,
                                               u32* __restrict__ mb2) {
  int i = blockIdx.x * 256 + threadIdx.x;
  if (blockIdx.x == 0 && threadIdx.x < NGRAPH) {
    mset(mb2, threadIdx.x * NPG);
    mset(mb1, threadIdx.x * NPG);
  }
  if (i >= N_EDGES / 4) return;
  int4 d = dst4[i], s = src4[i];
  if (d.x % NPG == 0) { mset(mb2, s.x); mset(mb1, s.x); }
  if (d.y % NPG == 0) { mset(mb2, s.y); mset(mb1, s.y); }
  if (d.z % NPG == 0) { mset(mb2, s.z); mset(mb1, s.z); }
  if (d.w % NPG == 0) { mset(mb2, s.w); mset(mb1, s.w); }
}

__global__ __launch_bounds__(256) void k_scan2(const int4* __restrict__ src4,
                                               const int4* __restrict__ dst4,
                                               const u32* __restrict__ mb2,
                                               u32* __restrict__ mb1) {
  int i = blockIdx.x * 256 + threadIdx.x;
  if (i >= N_EDGES / 4) return;
  int4 d = dst4[i], s = src4[i];
  if (mbit(mb2, d.x)) mset(mb1, s.x);
  if (mbit(mb2, d.y)) mset(mb1, s.y);
  if (mbit(mb2, d.z)) mset(mb1, s.z);
  if (mbit(mb2, d.w)) mset(mb1, s.w);
}

__global__ __launch_bounds__(256) void k_scan1(const int4* __restrict__ dst4,
                                               const u32* __restrict__ mb1,
                                               int* __restrict__ deg) {
  int i = blockIdx.x * 256 + threadIdx.x;
  if (i >= N_EDGES / 4) return;
  int4 d = dst4[i];
  if (mbit(mb1, d.x)) atomicAdd(&deg[d.x], 1);
  if (mbit(mb1, d.y)) atomicAdd(&deg[d.y], 1);
  if (mbit(mb1, d.z)) atomicAdd(&deg[d.z], 1);
  if (mbit(mb1, d.w)) atomicAdd(&deg[d.w], 1);
}

// CSR segment allocation (wave prefix-scan, 1 atomic/wave) + L1/L2 lists
__global__ __launch_bounds__(256) void k_alloc(const u32* __restrict__ mb1,
                                               const u32* __restrict__ mb2,
                                               const int* __restrict__ deg,
                                               int* __restrict__ offn,
                                               int* __restrict__ cur,
                                               int* __restrict__ L1,
                                               int* __restrict__ L2,
                                               int* __restrict__ ctrl) {
  int t = blockIdx.x * 256 + threadIdx.x;
  int lane = threadIdx.x & 63;
  bool inb = t < N_NODES;
  bool mk1 = inb && mbit(mb1, t);
  bool mk2 = inb && mbit(mb2, t);

  int v = mk1 ? deg[t] : 0;
  int incl = v;
#pragma unroll
  for (int o = 1; o < 64; o <<= 1) {
    int u = __shfl_up(incl, o, 64);
    if (lane >= o) incl += u;
  }
  int total = __shfl(incl, 63, 64);
  int sbase = 0;
  if (lane == 0 && total > 0) sbase = atomicAdd(&ctrl[C_SLOT], total);
  sbase = __shfl(sbase, 0, 64);
  int myoff = sbase + incl - v;
  if (mk1) { offn[t] = myoff; cur[t] = myoff; }

  u64 bal = __ballot(mk1);
  int pos = __popcll(bal & ((1ull << lane) - 1ull));
  int lbase = 0;
  if (lane == 0 && bal) lbase = atomicAdd(&ctrl[C_L1], __popcll(bal));
  lbase = __shfl(lbase, 0, 64);
  if (mk1 && lbase + pos < CAP_L1) L1[lbase + pos] = t;

  u64 bal2 = __ballot(mk2);
  int pos2 = __popcll(bal2 & ((1ull << lane) - 1ull));
  int lbase2 = 0;
  if (lane == 0 && bal2) lbase2 = atomicAdd(&ctrl[C_L2], __popcll(bal2));
  lbase2 = __shfl(lbase2, 0, 64);
  if (mk2 && lbase2 + pos2 < CAP_L2) L2[lbase2 + pos2] = t;
}

// scatter edges into CSR — ONLY distributed cur[] atomics, no contested counters
__global__ __launch_bounds__(256) void k_scatter(const int4* __restrict__ src4,
                                                 const int4* __restrict__ dst4,
                                                 const u32* __restrict__ mb1,
                                                 int* __restrict__ cur,
                                                 int2* __restrict__ csr_se,
                                                 int* __restrict__ csr_dst) {
  int i = blockIdx.x * 256 + threadIdx.x;
  if (i >= N_EDGES / 4) return;
  int4 dv = dst4[i], sv = src4[i];
  int ds[4] = {dv.x, dv.y, dv.z, dv.w};
  int ss[4] = {sv.x, sv.y, sv.z, sv.w};
#pragma unroll
  for (int j = 0; j < 4; ++j) {
    int d = ds[j];
    if (!mbit(mb1, d)) continue;
    int p = atomicAdd(&cur[d], 1);
    if (p < CAP_SLOTS) {
      csr_se[p] = make_int2(ss[j], i * 4 + j);
      csr_dst[p] = d;
    }
  }
}

// build E2/E3 packed lists {p, src, dst, e} from the ~29k CSR slots
__global__ __launch_bounds__(256) void k_lists(const int2* __restrict__ csr_se,
                                               const int* __restrict__ csr_dst,
                                               const u32* __restrict__ mb2,
                                               int4* __restrict__ E2,
                                               int4* __restrict__ E3,
                                               int* __restrict__ ctrl) {
  int ns = ctrl[C_SLOT];
  if (ns > CAP_SLOTS) ns = CAP_SLOTS;
  int lane = threadIdx.x & 63;
  int total = (ns + 255) & ~255;
  for (int p = blockIdx.x * 256 + threadIdx.x; p < total; p += gridDim.x * 256) {
    bool inb = p < ns;
    int d = inb ? csr_dst[p] : 0;
    bool e2 = inb && mbit(mb2, d);
    bool e3 = inb && (d % NPG == 0);
    int2 se = (e2 || e3) ? csr_se[p] : make_int2(0, 0);
    u64 bal = __ballot(e2);
    if (bal) {
      int base = 0;
      if (lane == 0) base = atomicAdd(&ctrl[C_E2], __popcll(bal));
      base = __shfl(base, 0, 64);
      int pos = __popcll(bal & ((1ull << lane) - 1ull));
      if (e2 && base + pos < CAP_E2) E2[base + pos] = make_int4(p, se.x, d, se.y);
    }
    u64 bal3 = __ballot(e3);
    if (bal3) {
      int base = 0;
      if (lane == 0) base = atomicAdd(&ctrl[C_E3], __popcll(bal3));
      base = __shfl(base, 0, 64);
      int pos = __popcll(bal3 & ((1ull << lane) - 1ull));
      if (e3 && base + pos < CAP_E3) E3[base + pos] = make_int4(p, se.x, d, se.y);
    }
  }
}

// concat [ws;wm] -> [384][128] for node-layer GEMMs
__global__ __launch_bounds__(256) void k_wcat(const float* __restrict__ ws1, const float* __restrict__ wm1,
                                              const float* __restrict__ ws2, const float* __restrict__ wm2,
                                              const float* __restrict__ ws3, const float* __restrict__ wm3,
                                              float* __restrict__ w1, float* __restrict__ w2,
                                              float* __restrict__ w3) {
  int t = blockIdx.x * 256 + threadIdx.x;
  if (t >= 384 * D) return;
  float v1, v2, v3;
  if (t < 128 * D) { v1 = ws1[t]; v2 = ws2[t]; v3 = ws3[t]; }
  else { int u = t - 128 * D; v1 = wm1[u]; v2 = wm2[u]; v3 = wm3[u]; }
  w1[t] = v1; w2[t] = v2; w3[t] = v3;
}

// ---------------- gathers: dense A rows [x | sx | se], K=384 ----------------

__global__ __launch_bounds__(256) void k_gat_node(const int* __restrict__ tok,
                                                  const float* __restrict__ emb,
                                                  const float* __restrict__ xin,
                                                  const float* __restrict__ attr,
                                                  const float* __restrict__ wproj,
                                                  const float* __restrict__ bproj,
                                                  const u16* __restrict__ ea,
                                                  const int2* __restrict__ csr_se,
                                                  const int* __restrict__ offn,
                                                  const int* __restrict__ cur,
                                                  const int* __restrict__ L,
                                                  const int* __restrict__ ctrl, int slot, int cap,
                                                  float* __restrict__ A,
                                                  float* __restrict__ degf) {
  int n_ = L ? ctrl[slot] : NGRAPH;
  if (n_ > cap) n_ = cap;
  int sub = threadIdx.x >> 5, q = threadIdx.x & 31;
  for (int i = blockIdx.x * 8 + sub; i < n_; i += gridDim.x * 8) {
    int n = L ? L[i] : i * NPG;
    int o = offn[n], end = cur[n];
    float dgf = (float)(end - o);
    float4 sx = make_float4(0.f, 0.f, 0.f, 0.f);
    float4 se = make_float4(0.f, 0.f, 0.f, 0.f);
    float4 xn;
    if (tok) {
      float4 sa = make_float4(0.f, 0.f, 0.f, 0.f);
      for (int p = o; p < end; ++p) {
        int2 se2 = csr_se[p];
        add4(sx, ((const float4*)(emb + (size_t)tok[se2.x] * D))[q]);
        add4(sa, ((const float4*)(attr + (size_t)se2.y * 16))[q & 3]);
      }
      float4 bp = ((const float4*)bproj)[q];
      se = make_float4(bp.x * dgf, bp.y * dgf, bp.z * dgf, bp.w * dgf);
      const float4* wp = (const float4*)wproj;
#pragma unroll
      for (int k4 = 0; k4 < 4; ++k4) {
        float4 xv = shfl4(sa, k4);
        fma4(se, xv.x, wp[(k4 * 4 + 0) * 32 + q]);
        fma4(se, xv.y, wp[(k4 * 4 + 1) * 32 + q]);
        fma4(se, xv.z, wp[(k4 * 4 + 2) * 32 + q]);
        fma4(se, xv.w, wp[(k4 * 4 + 3) * 32 + q]);
      }
      xn = ((const float4*)(emb + (size_t)tok[n] * D))[q];
    } else {
      for (int p = o; p < end; ++p) {
        int s = csr_se[p].x;
        add4(sx, ((const float4*)(xin + (size_t)s * D))[q]);
        add4(se, bf4(((const uint2*)(ea + (size_t)p * D))[q]));
      }
      xn = ((const float4*)(xin + (size_t)n * D))[q];
    }
    float4* Ar = (float4*)(A + (size_t)i * 384);
    Ar[q] = xn;
    Ar[32 + q] = sx;
    Ar[64 + q] = se;
    if (q == 0) degf[i] = dgf;
  }
}

__global__ __launch_bounds__(256) void k_gat_edge(const int* __restrict__ tok,
                                                  const float* __restrict__ emb,
                                                  const float* __restrict__ xin,
                                                  const float* __restrict__ attr,
                                                  const float* __restrict__ wproj,
                                                  const float* __restrict__ bproj,
                                                  const u16* __restrict__ ea,
                                                  const int4* __restrict__ EL,
                                                  const int* __restrict__ ctrl, int slot, int cap,
                                                  float* __restrict__ A) {
  int n_ = ctrl[slot];
  if (n_ > cap) n_ = cap;
  int sub = threadIdx.x >> 5, q = threadIdx.x & 31;
  for (int i = blockIdx.x * 8 + sub; i < n_; i += gridDim.x * 8) {
    int4 t = EL[i];
    int p = t.x, s = t.y, d = t.z, e = t.w;
    float4 xd, xs, ev;
    if (tok) {
      xd = ((const float4*)(emb + (size_t)tok[d] * D))[q];
      xs = ((const float4*)(emb + (size_t)tok[s] * D))[q];
      float4 av = ((const float4*)(attr + (size_t)e * 16))[q & 3];
      ev = ((const float4*)bproj)[q];
      const float4* wp = (const float4*)wproj;
#pragma unroll
      for (int k4 = 0; k4 < 4; ++k4) {
        float4 xv = shfl4(av, k4);
        fma4(ev, xv.x, wp[(k4 * 4 + 0) * 32 + q]);
        fma4(ev, xv.y, wp[(k4 * 4 + 1) * 32 + q]);
        fma4(ev, xv.z, wp[(k4 * 4 + 2) * 32 + q]);
        fma4(ev, xv.w, wp[(k4 * 4 + 3) * 32 + q]);
      }
    } else {
      xd = ((const float4*)(xin + (size_t)d * D))[q];
      xs = ((const float4*)(xin + (size_t)s * D))[q];
      ev = bf4(((const uint2*)(ea + (size_t)p * D))[q]);
    }
    float4* Ar = (float4*)(A + (size_t)i * 384);
    Ar[q] = xd;
    Ar[32 + q] = xs;
    Ar[64 + q] = ev;
  }
}

// ---------------- batched LDS-staged GEMM ----------------
// C[M][128] = A[M][384] @ W[384][128] + epilogue. 32-row tiles, W staged in LDS
// 64 rows at a time (32 KB). Up to 2 jobs per launch, tiles interleaved.

struct GJob {
  const float* A;
  const float* W;
  const float* bias;
  const float* bm;     // null for edge jobs
  const float* degf;   // null for edge jobs
  const int* L;        // node list or null (row index direct)
  const int4* EL;      // edge list (bf16 out slot) or null
  float* outf;
  u16* outb;
  int slot;            // ctrl slot for M, or -1 -> NGRAPH
  int cap;
  int relu;
};

__global__ __launch_bounds__(256) void k_gemm_b(GJob J0, GJob J1, int njobs,
                                                const int* __restrict__ ctrl) {
  __shared__ float Wlds[8192];  // 32 KB: 64 rows x 128 cols
  int sub = threadIdx.x >> 5, q = threadIdx.x & 31;
  int M0 = J0.slot < 0 ? NGRAPH : ctrl[J0.slot];
  if (M0 > J0.cap) M0 = J0.cap;
  int M1 = 0;
  if (njobs > 1) {
    M1 = J1.slot < 0 ? NGRAPH : ctrl[J1.slot];
    if (M1 > J1.cap) M1 = J1.cap;
  }
  int nt0 = (M0 + 31) >> 5, nt1 = (M1 + 31) >> 5;
  for (int g = blockIdx.x; g < nt0 + nt1; g += gridDim.x) {
    const GJob& J = (g < nt0) ? J0 : J1;
    int M = (g < nt0) ? M0 : M1;
    int tile = (g < nt0) ? g : g - nt0;
    int r0 = tile * 32 + sub * 4;
    int rr[4];
#pragma unroll
    for (int r = 0; r < 4; ++r) {
      int row = r0 + r;
      rr[r] = row < M ? row : M - 1;
    }
    float4 bias4 = ((const float4*)J.bias)[q];
    float4 acc[4] = {bias4, bias4, bias4, bias4};
    const float4* W4 = (const float4*)J.W;
    for (int seg = 0; seg < 3; ++seg) {
      float4 af[4];
#pragma unroll
      for (int r = 0; r < 4; ++r)
        af[r] = ((const float4*)(J.A + (size_t)rr[r] * 384))[seg * 32 + q];
      for (int h = 0; h < 2; ++h) {
        __syncthreads();  // previous LDS consumers done
        const float4* wsrc = W4 + (size_t)(seg * 128 + h * 64) * 32;
#pragma unroll
        for (int u = 0; u < 8; ++u)
          ((float4*)Wlds)[threadIdx.x + u * 256] = wsrc[threadIdx.x + u * 256];
        __syncthreads();
#pragma unroll
        for (int k4l = 0; k4l < 16; ++k4l) {
          int k4 = h * 16 + k4l;
          float4 w0 = ((const float4*)Wlds)[(k4l * 4 + 0) * 32 + q];
          float4 w1 = ((const float4*)Wlds)[(k4l * 4 + 1) * 32 + q];
          float4 w2 = ((const float4*)Wlds)[(k4l * 4 + 2) * 32 + q];
          float4 w3 = ((const float4*)Wlds)[(k4l * 4 + 3) * 32 + q];
#pragma unroll
          for (int r = 0; r < 4; ++r) {
            float4 xv = shfl4(af[r], k4);
            fma4(acc[r], xv.x, w0);
            fma4(acc[r], xv.y, w1);
            fma4(acc[r], xv.z, w2);
            fma4(acc[r], xv.w, w3);
          }
        }
      }
    }
#pragma unroll
    for (int r = 0; r < 4; ++r) {
      int row = r0 + r;
      if (row < M) {
        float4 a = acc[r];
        if (J.degf) {
          float dg = J.degf[row];
          float4 bm4 = ((const float4*)J.bm)[q];
          a.x = fmaf(dg, bm4.x, a.x);
          a.y = fmaf(dg, bm4.y, a.y);
          a.z = fmaf(dg, bm4.z, a.z);
          a.w = fmaf(dg, bm4.w, a.w);
        }
        if (J.relu) {
          a.x = fmaxf(a.x, 0.f);
          a.y = fmaxf(a.y, 0.f);
          a.z = fmaxf(a.z, 0.f);
          a.w = fmaxf(a.w, 0.f);
        }
        if (J.outb) {
          int p = J.EL[row].x;
          u32 p0 = (u32)f2bf(a.x) | ((u32)f2bf(a.y) << 16);
          u32 p1 = (u32)f2bf(a.z) | ((u32)f2bf(a.w) << 16);
          ((uint2*)(J.outb + (size_t)p * D))[q] = make_uint2(p0, p1);
        } else {
          int idx = J.L ? J.L[row] : row;
          ((float4*)(J.outf + (size_t)idx * D))[q] = a;
        }
      }
    }
  }
}

extern "C" void kernel_launch(void* const* d_in, const int* in_sizes, int n_in,
                              void* d_out, int out_size, void* d_ws, size_t ws_size,
                              hipStream_t stream) {
  const int* tok = (const int*)d_in[0];
  const int* eidx = (const int*)d_in[1];
  const int4* src4 = (const int4*)eidx;
  const int4* dst4 = (const int4*)(eidx + N_EDGES);
  const float* attr = (const float*)d_in[2];
  const float* emb = (const float*)d_in[4];
  const float* w_proj = (const float*)d_in[5];
  const float* b_proj = (const float*)d_in[6];
  const float *ws_[3], *bs_[3], *wm_[3], *bm_[3], *we_[3], *be_[3];
  for (int i = 0; i < 3; ++i) {
    ws_[i] = (const float*)d_in[7 + 6 * i];
    bs_[i] = (const float*)d_in[8 + 6 * i];
    wm_[i] = (const float*)d_in[9 + 6 * i];
    bm_[i] = (const float*)d_in[10 + 6 * i];
    we_[i] = (const float*)d_in[11 + 6 * i];
    be_[i] = (const float*)d_in[12 + 6 * i];
  }
  float* out = (float*)d_out;

  // ---- workspace ----
  char* base = (char*)d_ws;
  size_t o = 0;
  int* ctrl = (int*)(base + o); o += 256;
  u32* mb1 = (u32*)(base + o); o += MBW * 4;
  u32* mb2 = (u32*)(base + o); o += MBW * 4;
  int* deg = (int*)(base + o); o += (size_t)N_NODES * 4;
  size_t zero_bytes = o;  // ctrl + masks + deg zeroed each call
  int* offn = (int*)(base + o); o += (size_t)N_NODES * 4;
  int* cur = (int*)(base + o); o += (size_t)N_NODES * 4;
  int2* csr_se = (int2*)(base + o); o += (size_t)CAP_SLOTS * 8;
  int* csr_dst = (int*)(base + o); o += (size_t)CAP_SLOTS * 4;
  o = (o + 15) & ~(size_t)15;
  int4* E2 = (int4*)(base + o); o += (size_t)CAP_E2 * 16;
  int4* E3 = (int4*)(base + o); o += (size_t)CAP_E3 * 16;
  int* L1 = (int*)(base + o); o += (size_t)CAP_L1 * 4;
  int* L2 = (int*)(base + o); o += (size_t)CAP_L2 * 4;
  float* degf = (float*)(base + o); o += (size_t)CAP_L1 * 4;
  float* w1c = (float*)(base + o); o += (size_t)384 * D * 4;
  float* w2c = (float*)(base + o); o += (size_t)384 * D * 4;
  float* w3c = (float*)(base + o); o += (size_t)384 * D * 4;
  o = (o + 511) & ~(size_t)511;
  float* A_n = (float*)(base + o); o += (size_t)CAP_L1 * 384 * 4;  // 25 MB
  float* A_e = (float*)(base + o); o += (size_t)CAP_E2 * 384 * 4;  // 25 MB
  float* x1 = (float*)(base + o); o += (size_t)N_NODES * D * 4;    // 51 MB
  float* x2 = (float*)(base + o); o += (size_t)N_NODES * D * 4;    // 51 MB
  u16* ea = (u16*)(base + o); o += (size_t)CAP_SLOTS * D * 2;      // 16 MB

  hipMemsetAsync(d_ws, 0, zero_bytes, stream);

  dim3 B(256);
  const int EG4 = (N_EDGES / 4 + 255) / 256;  // 586
  const int NG = (N_NODES + 255) / 256;       // 391

  // cone + CSR
  k_scan3<<<EG4, B, 0, stream>>>(src4, dst4, mb1, mb2);
  k_scan2<<<EG4, B, 0, stream>>>(src4, dst4, mb2, mb1);
  k_scan1<<<EG4, B, 0, stream>>>(dst4, mb1, deg);
  k_alloc<<<NG, B, 0, stream>>>(mb1, mb2, deg, offn, cur, L1, L2, ctrl);
  k_scatter<<<EG4, B, 0, stream>>>(src4, dst4, mb1, cur, csr_se, csr_dst);
  k_lists<<<32, B, 0, stream>>>(csr_se, csr_dst, mb2, E2, E3, ctrl);
  k_wcat<<<192, B, 0, stream>>>(ws_[0], wm_[0], ws_[1], wm_[1], ws_[2], wm_[2],
                                w1c, w2c, w3c);

  GJob jn, je, jz;
  // ---- stage 1 ----
  k_gat_node<<<640, B, 0, stream>>>(tok, emb, nullptr, attr, w_proj, b_proj, ea,
                                    csr_se, offn, cur, L1, ctrl, C_L1, CAP_L1,
                                    A_n, degf);
  k_gat_edge<<<640, B, 0, stream>>>(tok, emb, nullptr, attr, w_proj, b_proj, ea,
                                    E2, ctrl, C_E2, CAP_E2, A_e);
  jn = {A_n, w1c, bs_[0], bm_[0], degf, L1, nullptr, x1, nullptr, C_L1, CAP_L1, 1};
  je = {A_e, we_[0], be_[0], nullptr, nullptr, nullptr, E2, nullptr, ea, C_E2, CAP_E2, 1};
  k_gemm_b<<<512, B, 0, stream>>>(jn, je, 2, ctrl);

  // ---- stage 2 ----
  k_gat_node<<<96, B, 0, stream>>>(nullptr, nullptr, x1, nullptr, nullptr, nullptr, ea,
                                   csr_se, offn, cur, L2, ctrl, C_L2, CAP_L2,
                                   A_n, degf);
  k_gat_edge<<<96, B, 0, stream>>>(nullptr, nullptr, x1, nullptr, nullptr, nullptr, ea,
                                   E3, ctrl, C_E3, CAP_E3, A_e);
  jn = {A_n, w2c, bs_[1], bm_[1], degf, L2, nullptr, x2, nullptr, C_L2, CAP_L2, 1};
  je = {A_e, we_[1], be_[1], nullptr, nullptr, nullptr, E3, nullptr, ea, C_E3, CAP_E3, 1};
  k_gemm_b<<<512, B, 0, stream>>>(jn, je, 2, ctrl);

  // ---- stage 3: masters only, no relu ----
  k_gat_node<<<16, B, 0, stream>>>(nullptr, nullptr, x2, nullptr, nullptr, nullptr, ea,
                                   csr_se, offn, cur, nullptr, ctrl, -1, NGRAPH,
                                   A_n, degf);
  jn = {A_n, w3c, bs_[2], bm_[2], degf, nullptr, nullptr, out, nullptr, -1, NGRAPH, 0};
  jz = {};
  k_gemm_b<<<128, B, 0, stream>>>(jn, jz, 1, ctrl);
}

// Round 7
// 214.956 us; speedup vs baseline: 1.6395x; 1.0493x over previous
//
#include <hip/hip_runtime.h>

typedef unsigned short u16;
typedef unsigned int u32;
typedef unsigned long long u64;

#define N_NODES 100000
#define N_EDGES 600000
#define D 128
#define NPG 1000
#define NGRAPH 100
#define MBW 3136          // mask words (padded) >= ceil(100000/32)

#define CAP_SLOTS 65536   // CSR slots (expected ~29.4k)
#define CAP_L1    16384   // S1 nodes (expected ~4.9k)
#define CAP_L2    4096    // S2 nodes (expected ~700)
#define CAP_E2    16384   // edges into S2 (expected ~4.2k)
#define CAP_E3    4096    // edges into masters (expected ~600)

#define C_SLOT 0
#define C_L1   1
#define C_L2   2
#define C_E2   3
#define C_E3   4

__device__ __forceinline__ float bf2f(u16 u) {
  return __uint_as_float(((u32)u) << 16);
}
__device__ __forceinline__ u16 f2bf(float f) {
  u32 u = __float_as_uint(f);
  u32 r = (u + 0x7FFFu + ((u >> 16) & 1u)) >> 16;  // RNE
  return (u16)r;
}
__device__ __forceinline__ void fma4(float4& acc, float a, const float4 w) {
  acc.x = fmaf(a, w.x, acc.x);
  acc.y = fmaf(a, w.y, acc.y);
  acc.z = fmaf(a, w.z, acc.z);
  acc.w = fmaf(a, w.w, acc.w);
}
__device__ __forceinline__ float4 bf4(uint2 u) {
  return make_float4(bf2f((u16)(u.x & 0xFFFFu)), bf2f((u16)(u.x >> 16)),
                     bf2f((u16)(u.y & 0xFFFFu)), bf2f((u16)(u.y >> 16)));
}
__device__ __forceinline__ void add4(float4& a, const float4 b) {
  a.x += b.x; a.y += b.y; a.z += b.z; a.w += b.w;
}
__device__ __forceinline__ float4 shfl4(float4 v, int lane) {
  return make_float4(__shfl(v.x, lane, 32), __shfl(v.y, lane, 32),
                     __shfl(v.z, lane, 32), __shfl(v.w, lane, 32));
}
__device__ __forceinline__ int mbit(const u32* __restrict__ mb, int n) {
  return (mb[n >> 5] >> (n & 31)) & 1u;
}
__device__ __forceinline__ void mset(u32* __restrict__ mb, int n) {
  atomicOr(&mb[n >> 5], 1u << (n & 31));
}

// ---------------- cone construction ----------------
// invariant: mb1 >= mb2 at every write

__global__ __launch_bounds__(256) void k_scan3(const int4* __restrict__ src4,
                                               const int4* __restrict__ dst4,
                                               u32* __restrict__ mb1,
                                               u32* __restrict__ mb2) {
  int i = blockIdx.x * 256 + threadIdx.x;
  if (blockIdx.x == 0 && threadIdx.x < NGRAPH) {
    mset(mb2, threadIdx.x * NPG);
    mset(mb1, threadIdx.x * NPG);
  }
  if (i >= N_EDGES / 4) return;
  int4 d = dst4[i], s = src4[i];
  if (d.x % NPG == 0) { mset(mb2, s.x); mset(mb1, s.x); }
  if (d.y % NPG == 0) { mset(mb2, s.y); mset(mb1, s.y); }
  if (d.z % NPG == 0) { mset(mb2, s.z); mset(mb1, s.z); }
  if (d.w % NPG == 0) { mset(mb2, s.w); mset(mb1, s.w); }
}

__global__ __launch_bounds__(256) void k_scan2(const int4* __restrict__ src4,
                                               const int4* __restrict__ dst4,
                                               const u32* __restrict__ mb2,
                                               u32* __restrict__ mb1) {
  int i = blockIdx.x * 256 + threadIdx.x;
  if (i >= N_EDGES / 4) return;
  int4 d = dst4[i], s = src4[i];
  if (mbit(mb2, d.x)) mset(mb1, s.x);
  if (mbit(mb2, d.y)) mset(mb1, s.y);
  if (mbit(mb2, d.z)) mset(mb1, s.z);
  if (mbit(mb2, d.w)) mset(mb1, s.w);
}

__global__ __launch_bounds__(256) void k_scan1(const int4* __restrict__ dst4,
                                               const u32* __restrict__ mb1,
                                               int* __restrict__ deg) {
  int i = blockIdx.x * 256 + threadIdx.x;
  if (i >= N_EDGES / 4) return;
  int4 d = dst4[i];
  if (mbit(mb1, d.x)) atomicAdd(&deg[d.x], 1);
  if (mbit(mb1, d.y)) atomicAdd(&deg[d.y], 1);
  if (mbit(mb1, d.z)) atomicAdd(&deg[d.z], 1);
  if (mbit(mb1, d.w)) atomicAdd(&deg[d.w], 1);
}

// CSR segment allocation (wave prefix-scan, 1 atomic/wave) + L1/L2 lists
__global__ __launch_bounds__(256) void k_alloc(const u32* __restrict__ mb1,
                                               const u32* __restrict__ mb2,
                                               const int* __restrict__ deg,
                                               int* __restrict__ offn,
                                               int* __restrict__ cur,
                                               int* __restrict__ L1,
                                               int* __restrict__ L2,
                                               int* __restrict__ ctrl) {
  int t = blockIdx.x * 256 + threadIdx.x;
  int lane = threadIdx.x & 63;
  bool inb = t < N_NODES;
  bool mk1 = inb && mbit(mb1, t);
  bool mk2 = inb && mbit(mb2, t);

  int v = mk1 ? deg[t] : 0;
  int incl = v;
#pragma unroll
  for (int o = 1; o < 64; o <<= 1) {
    int u = __shfl_up(incl, o, 64);
    if (lane >= o) incl += u;
  }
  int total = __shfl(incl, 63, 64);
  int sbase = 0;
  if (lane == 0 && total > 0) sbase = atomicAdd(&ctrl[C_SLOT], total);
  sbase = __shfl(sbase, 0, 64);
  int myoff = sbase + incl - v;
  if (mk1) { offn[t] = myoff; cur[t] = myoff; }

  u64 bal = __ballot(mk1);
  int pos = __popcll(bal & ((1ull << lane) - 1ull));
  int lbase = 0;
  if (lane == 0 && bal) lbase = atomicAdd(&ctrl[C_L1], __popcll(bal));
  lbase = __shfl(lbase, 0, 64);
  if (mk1 && lbase + pos < CAP_L1) L1[lbase + pos] = t;

  u64 bal2 = __ballot(mk2);
  int pos2 = __popcll(bal2 & ((1ull << lane) - 1ull));
  int lbase2 = 0;
  if (lane == 0 && bal2) lbase2 = atomicAdd(&ctrl[C_L2], __popcll(bal2));
  lbase2 = __shfl(lbase2, 0, 64);
  if (mk2 && lbase2 + pos2 < CAP_L2) L2[lbase2 + pos2] = t;
}

// scatter edges into CSR — only distributed cur[] atomics
__global__ __launch_bounds__(256) void k_scatter(const int4* __restrict__ src4,
                                                 const int4* __restrict__ dst4,
                                                 const u32* __restrict__ mb1,
                                                 int* __restrict__ cur,
                                                 int2* __restrict__ csr_se,
                                                 int* __restrict__ csr_dst) {
  int i = blockIdx.x * 256 + threadIdx.x;
  if (i >= N_EDGES / 4) return;
  int4 dv = dst4[i], sv = src4[i];
  int ds[4] = {dv.x, dv.y, dv.z, dv.w};
  int ss[4] = {sv.x, sv.y, sv.z, sv.w};
#pragma unroll
  for (int j = 0; j < 4; ++j) {
    int d = ds[j];
    if (!mbit(mb1, d)) continue;
    int p = atomicAdd(&cur[d], 1);
    if (p < CAP_SLOTS) {
      csr_se[p] = make_int2(ss[j], i * 4 + j);
      csr_dst[p] = d;
    }
  }
}

// merged: blocks [0,192) concat [ws;wm] weights; blocks [192,224) build E2/E3 lists
__global__ __launch_bounds__(256) void k_aux(const int2* __restrict__ csr_se,
                                             const int* __restrict__ csr_dst,
                                             const u32* __restrict__ mb2,
                                             int4* __restrict__ E2,
                                             int4* __restrict__ E3,
                                             int* __restrict__ ctrl,
                                             const float* __restrict__ ws1, const float* __restrict__ wm1,
                                             const float* __restrict__ ws2, const float* __restrict__ wm2,
                                             const float* __restrict__ ws3, const float* __restrict__ wm3,
                                             float* __restrict__ w1, float* __restrict__ w2,
                                             float* __restrict__ w3) {
  if (blockIdx.x < 192) {  // wcat: 192*256 == 384*128
    int t = blockIdx.x * 256 + threadIdx.x;
    float v1, v2, v3;
    if (t < 128 * D) { v1 = ws1[t]; v2 = ws2[t]; v3 = ws3[t]; }
    else { int u = t - 128 * D; v1 = wm1[u]; v2 = wm2[u]; v3 = wm3[u]; }
    w1[t] = v1; w2[t] = v2; w3[t] = v3;
    return;
  }
  int lb = blockIdx.x - 192;  // 32 list blocks
  int ns = ctrl[C_SLOT];
  if (ns > CAP_SLOTS) ns = CAP_SLOTS;
  int lane = threadIdx.x & 63;
  int total = (ns + 255) & ~255;
  for (int p = lb * 256 + threadIdx.x; p < total; p += 32 * 256) {
    bool inb = p < ns;
    int d = inb ? csr_dst[p] : 0;
    bool e2 = inb && mbit(mb2, d);
    bool e3 = inb && (d % NPG == 0);
    int2 se = (e2 || e3) ? csr_se[p] : make_int2(0, 0);
    u64 bal = __ballot(e2);
    if (bal) {
      int base = 0;
      if (lane == 0) base = atomicAdd(&ctrl[C_E2], __popcll(bal));
      base = __shfl(base, 0, 64);
      int pos = __popcll(bal & ((1ull << lane) - 1ull));
      if (e2 && base + pos < CAP_E2) E2[base + pos] = make_int4(p, se.x, d, se.y);
    }
    u64 bal3 = __ballot(e3);
    if (bal3) {
      int base = 0;
      if (lane == 0) base = atomicAdd(&ctrl[C_E3], __popcll(bal3));
      base = __shfl(base, 0, 64);
      int pos = __popcll(bal3 & ((1ull << lane) - 1ull));
      if (e3 && base + pos < CAP_E3) E3[base + pos] = make_int4(p, se.x, d, se.y);
    }
  }
}

// ---------------- gathers: dense A rows [x | sx | se], K=384 ----------------

__global__ __launch_bounds__(256) void k_gat_node(const int* __restrict__ tok,
                                                  const float* __restrict__ emb,
                                                  const float* __restrict__ xin,
                                                  const float* __restrict__ attr,
                                                  const float* __restrict__ wproj,
                                                  const float* __restrict__ bproj,
                                                  const u16* __restrict__ ea,
                                                  const int2* __restrict__ csr_se,
                                                  const int* __restrict__ offn,
                                                  const int* __restrict__ cur,
                                                  const int* __restrict__ L,
                                                  const int* __restrict__ ctrl, int slot, int cap,
                                                  float* __restrict__ A,
                                                  float* __restrict__ degf) {
  int n_ = L ? ctrl[slot] : NGRAPH;
  if (n_ > cap) n_ = cap;
  int sub = threadIdx.x >> 5, q = threadIdx.x & 31;
  for (int i = blockIdx.x * 8 + sub; i < n_; i += gridDim.x * 8) {
    int n = L ? L[i] : i * NPG;
    int o = offn[n], end = cur[n];
    float dgf = (float)(end - o);
    float4 sx = make_float4(0.f, 0.f, 0.f, 0.f);
    float4 se = make_float4(0.f, 0.f, 0.f, 0.f);
    float4 xn;
    if (tok) {
      float4 sa = make_float4(0.f, 0.f, 0.f, 0.f);
      for (int p = o; p < end; ++p) {
        int2 se2 = csr_se[p];
        add4(sx, ((const float4*)(emb + (size_t)tok[se2.x] * D))[q]);
        add4(sa, ((const float4*)(attr + (size_t)se2.y * 16))[q & 3]);
      }
      float4 bp = ((const float4*)bproj)[q];
      se = make_float4(bp.x * dgf, bp.y * dgf, bp.z * dgf, bp.w * dgf);
      const float4* wp = (const float4*)wproj;
#pragma unroll
      for (int k4 = 0; k4 < 4; ++k4) {
        float4 xv = shfl4(sa, k4);
        fma4(se, xv.x, wp[(k4 * 4 + 0) * 32 + q]);
        fma4(se, xv.y, wp[(k4 * 4 + 1) * 32 + q]);
        fma4(se, xv.z, wp[(k4 * 4 + 2) * 32 + q]);
        fma4(se, xv.w, wp[(k4 * 4 + 3) * 32 + q]);
      }
      xn = ((const float4*)(emb + (size_t)tok[n] * D))[q];
    } else {
      for (int p = o; p < end; ++p) {
        int s = csr_se[p].x;
        add4(sx, ((const float4*)(xin + (size_t)s * D))[q]);
        add4(se, bf4(((const uint2*)(ea + (size_t)p * D))[q]));
      }
      xn = ((const float4*)(xin + (size_t)n * D))[q];
    }
    float4* Ar = (float4*)(A + (size_t)i * 384);
    Ar[q] = xn;
    Ar[32 + q] = sx;
    Ar[64 + q] = se;
    if (q == 0) degf[i] = dgf;
  }
}

__global__ __launch_bounds__(256) void k_gat_edge(const int* __restrict__ tok,
                                                  const float* __restrict__ emb,
                                                  const float* __restrict__ xin,
                                                  const float* __restrict__ attr,
                                                  const float* __restrict__ wproj,
                                                  const float* __restrict__ bproj,
                                                  const u16* __restrict__ ea,
                                                  const int4* __restrict__ EL,
                                                  const int* __restrict__ ctrl, int slot, int cap,
                                                  float* __restrict__ A) {
  int n_ = ctrl[slot];
  if (n_ > cap) n_ = cap;
  int sub = threadIdx.x >> 5, q = threadIdx.x & 31;
  for (int i = blockIdx.x * 8 + sub; i < n_; i += gridDim.x * 8) {
    int4 t = EL[i];
    int p = t.x, s = t.y, d = t.z, e = t.w;
    float4 xd, xs, ev;
    if (tok) {
      xd = ((const float4*)(emb + (size_t)tok[d] * D))[q];
      xs = ((const float4*)(emb + (size_t)tok[s] * D))[q];
      float4 av = ((const float4*)(attr + (size_t)e * 16))[q & 3];
      ev = ((const float4*)bproj)[q];
      const float4* wp = (const float4*)wproj;
#pragma unroll
      for (int k4 = 0; k4 < 4; ++k4) {
        float4 xv = shfl4(av, k4);
        fma4(ev, xv.x, wp[(k4 * 4 + 0) * 32 + q]);
        fma4(ev, xv.y, wp[(k4 * 4 + 1) * 32 + q]);
        fma4(ev, xv.z, wp[(k4 * 4 + 2) * 32 + q]);
        fma4(ev, xv.w, wp[(k4 * 4 + 3) * 32 + q]);
      }
    } else {
      xd = ((const float4*)(xin + (size_t)d * D))[q];
      xs = ((const float4*)(xin + (size_t)s * D))[q];
      ev = bf4(((const uint2*)(ea + (size_t)p * D))[q]);
    }
    float4* Ar = (float4*)(A + (size_t)i * 384);
    Ar[q] = xd;
    Ar[32 + q] = xs;
    Ar[64 + q] = ev;
  }
}

// ---------------- batched LDS-staged GEMM (A-broadcast, no cross-lane ops) ----
// C[M][128] = A[M][384] @ W[384][128] + epilogue.
// Tile = 16 rows/block (256 thr). Wave wv owns rows wv*4..wv*4+3; lane q owns
// cols 2q,2q+1. A-tile (16x384, 24KB) staged once per tile; W staged in 64-row
// halves (32KB). Inner loop: A via wave-uniform ds_read_b128 (broadcast), W via
// ds_read_b64 — zero bpermute/shfl.

struct GJob {
  const float* A;
  const float* W;
  const float* bias;
  const float* bm;     // null for edge jobs
  const float* degf;   // null for edge jobs
  const int* L;        // node list or null (row index direct)
  const int4* EL;      // edge list (bf16 out slot) or null
  float* outf;
  u16* outb;
  int slot;            // ctrl slot for M, or -1 -> NGRAPH
  int cap;
  int relu;
};

__global__ __launch_bounds__(256) void k_gemm_b(GJob J0, GJob J1, int njobs,
                                                const int* __restrict__ ctrl) {
  __shared__ float Alds[16 * 384];   // 24 KB
  __shared__ float Wlds[64 * 128];   // 32 KB
  int q = threadIdx.x & 63, wv = threadIdx.x >> 6;
  int M0 = J0.slot < 0 ? NGRAPH : ctrl[J0.slot];
  if (M0 > J0.cap) M0 = J0.cap;
  int M1 = 0;
  if (njobs > 1) {
    M1 = J1.slot < 0 ? NGRAPH : ctrl[J1.slot];
    if (M1 > J1.cap) M1 = J1.cap;
  }
  int nt0 = (M0 + 15) >> 4, nt1 = (M1 + 15) >> 4;
  for (int g = blockIdx.x; g < nt0 + nt1; g += gridDim.x) {
    const GJob& J = (g < nt0) ? J0 : J1;
    int M = (g < nt0) ? M0 : M1;
    int tile = (g < nt0) ? g : g - nt0;
    __syncthreads();  // previous tile's LDS reads complete
    // stage A-tile: 16 rows x 96 float4
#pragma unroll
    for (int u = 0; u < 6; ++u) {
      int idx = threadIdx.x + u * 256;     // 0..1535
      int row = idx / 96, c4 = idx % 96;
      int gr = tile * 16 + row;
      if (gr > M - 1) gr = M - 1;
      ((float4*)Alds)[idx] = ((const float4*)(J.A + (size_t)gr * 384))[c4];
    }
    float2 bias2 = ((const float2*)J.bias)[q];
    float2 acc[4] = {bias2, bias2, bias2, bias2};
    const float4* W4 = (const float4*)J.W;
    const float4* Ar[4];
#pragma unroll
    for (int r = 0; r < 4; ++r) Ar[r] = (const float4*)(Alds + (wv * 4 + r) * 384);
    for (int seg = 0; seg < 3; ++seg) {
      for (int h = 0; h < 2; ++h) {
        __syncthreads();
        const float4* wsrc = W4 + (size_t)(seg * 128 + h * 64) * 32;
#pragma unroll
        for (int u = 0; u < 8; ++u)
          ((float4*)Wlds)[threadIdx.x + u * 256] = wsrc[threadIdx.x + u * 256];
        __syncthreads();
        int kb = seg * 32 + h * 16;
#pragma unroll
        for (int k4l = 0; k4l < 16; ++k4l) {
          float2 w0 = ((const float2*)Wlds)[(k4l * 4 + 0) * 64 + q];
          float2 w1 = ((const float2*)Wlds)[(k4l * 4 + 1) * 64 + q];
          float2 w2 = ((const float2*)Wlds)[(k4l * 4 + 2) * 64 + q];
          float2 w3 = ((const float2*)Wlds)[(k4l * 4 + 3) * 64 + q];
#pragma unroll
          for (int r = 0; r < 4; ++r) {
            float4 a = Ar[r][kb + k4l];   // wave-uniform -> broadcast
            acc[r].x = fmaf(a.x, w0.x, acc[r].x);
            acc[r].y = fmaf(a.x, w0.y, acc[r].y);
            acc[r].x = fmaf(a.y, w1.x, acc[r].x);
            acc[r].y = fmaf(a.y, w1.y, acc[r].y);
            acc[r].x = fmaf(a.z, w2.x, acc[r].x);
            acc[r].y = fmaf(a.z, w2.y, acc[r].y);
            acc[r].x = fmaf(a.w, w3.x, acc[r].x);
            acc[r].y = fmaf(a.w, w3.y, acc[r].y);
          }
        }
      }
    }
#pragma unroll
    for (int r = 0; r < 4; ++r) {
      int row = tile * 16 + wv * 4 + r;
      if (row < M) {
        float2 a = acc[r];
        if (J.degf) {
          float dg = J.degf[row];
          float2 bm2 = ((const float2*)J.bm)[q];
          a.x = fmaf(dg, bm2.x, a.x);
          a.y = fmaf(dg, bm2.y, a.y);
        }
        if (J.relu) {
          a.x = fmaxf(a.x, 0.f);
          a.y = fmaxf(a.y, 0.f);
        }
        if (J.outb) {
          int p = J.EL[row].x;
          u32 pk = (u32)f2bf(a.x) | ((u32)f2bf(a.y) << 16);
          ((u32*)(J.outb + (size_t)p * D))[q] = pk;
        } else {
          int idx = J.L ? J.L[row] : row;
          ((float2*)(J.outf + (size_t)idx * D))[q] = a;
        }
      }
    }
  }
}

extern "C" void kernel_launch(void* const* d_in, const int* in_sizes, int n_in,
                              void* d_out, int out_size, void* d_ws, size_t ws_size,
                              hipStream_t stream) {
  const int* tok = (const int*)d_in[0];
  const int* eidx = (const int*)d_in[1];
  const int4* src4 = (const int4*)eidx;
  const int4* dst4 = (const int4*)(eidx + N_EDGES);
  const float* attr = (const float*)d_in[2];
  const float* emb = (const float*)d_in[4];
  const float* w_proj = (const float*)d_in[5];
  const float* b_proj = (const float*)d_in[6];
  const float *ws_[3], *bs_[3], *wm_[3], *bm_[3], *we_[3], *be_[3];
  for (int i = 0; i < 3; ++i) {
    ws_[i] = (const float*)d_in[7 + 6 * i];
    bs_[i] = (const float*)d_in[8 + 6 * i];
    wm_[i] = (const float*)d_in[9 + 6 * i];
    bm_[i] = (const float*)d_in[10 + 6 * i];
    we_[i] = (const float*)d_in[11 + 6 * i];
    be_[i] = (const float*)d_in[12 + 6 * i];
  }
  float* out = (float*)d_out;

  // ---- workspace ----
  char* base = (char*)d_ws;
  size_t o = 0;
  int* ctrl = (int*)(base + o); o += 256;
  u32* mb1 = (u32*)(base + o); o += MBW * 4;
  u32* mb2 = (u32*)(base + o); o += MBW * 4;
  int* deg = (int*)(base + o); o += (size_t)N_NODES * 4;
  size_t zero_bytes = o;  // ctrl + masks + deg zeroed each call
  int* offn = (int*)(base + o); o += (size_t)N_NODES * 4;
  int* cur = (int*)(base + o); o += (size_t)N_NODES * 4;
  int2* csr_se = (int2*)(base + o); o += (size_t)CAP_SLOTS * 8;
  int* csr_dst = (int*)(base + o); o += (size_t)CAP_SLOTS * 4;
  o = (o + 15) & ~(size_t)15;
  int4* E2 = (int4*)(base + o); o += (size_t)CAP_E2 * 16;
  int4* E3 = (int4*)(base + o); o += (size_t)CAP_E3 * 16;
  int* L1 = (int*)(base + o); o += (size_t)CAP_L1 * 4;
  int* L2 = (int*)(base + o); o += (size_t)CAP_L2 * 4;
  float* degf = (float*)(base + o); o += (size_t)CAP_L1 * 4;
  float* w1c = (float*)(base + o); o += (size_t)384 * D * 4;
  float* w2c = (float*)(base + o); o += (size_t)384 * D * 4;
  float* w3c = (float*)(base + o); o += (size_t)384 * D * 4;
  o = (o + 511) & ~(size_t)511;
  float* A_n = (float*)(base + o); o += (size_t)CAP_L1 * 384 * 4;  // 25 MB
  float* A_e = (float*)(base + o); o += (size_t)CAP_E2 * 384 * 4;  // 25 MB
  float* x1 = (float*)(base + o); o += (size_t)N_NODES * D * 4;    // 51 MB
  float* x2 = (float*)(base + o); o += (size_t)N_NODES * D * 4;    // 51 MB
  u16* ea = (u16*)(base + o); o += (size_t)CAP_SLOTS * D * 2;      // 16 MB

  hipMemsetAsync(d_ws, 0, zero_bytes, stream);

  dim3 B(256);
  const int EG4 = (N_EDGES / 4 + 255) / 256;  // 586
  const int NG = (N_NODES + 255) / 256;       // 391

  // cone + CSR
  k_scan3<<<EG4, B, 0, stream>>>(src4, dst4, mb1, mb2);
  k_scan2<<<EG4, B, 0, stream>>>(src4, dst4, mb2, mb1);
  k_scan1<<<EG4, B, 0, stream>>>(dst4, mb1, deg);
  k_alloc<<<NG, B, 0, stream>>>(mb1, mb2, deg, offn, cur, L1, L2, ctrl);
  k_scatter<<<EG4, B, 0, stream>>>(src4, dst4, mb1, cur, csr_se, csr_dst);
  k_aux<<<224, B, 0, stream>>>(csr_se, csr_dst, mb2, E2, E3, ctrl,
                               ws_[0], wm_[0], ws_[1], wm_[1], ws_[2], wm_[2],
                               w1c, w2c, w3c);

  GJob jn, je, jz;
  // ---- stage 1 ----
  k_gat_node<<<640, B, 0, stream>>>(tok, emb, nullptr, attr, w_proj, b_proj, ea,
                                    csr_se, offn, cur, L1, ctrl, C_L1, CAP_L1,
                                    A_n, degf);
  k_gat_edge<<<640, B, 0, stream>>>(tok, emb, nullptr, attr, w_proj, b_proj, ea,
                                    E2, ctrl, C_E2, CAP_E2, A_e);
  jn = {A_n, w1c, bs_[0], bm_[0], degf, L1, nullptr, x1, nullptr, C_L1, CAP_L1, 1};
  je = {A_e, we_[0], be_[0], nullptr, nullptr, nullptr, E2, nullptr, ea, C_E2, CAP_E2, 1};
  k_gemm_b<<<512, B, 0, stream>>>(jn, je, 2, ctrl);

  // ---- stage 2 ----
  k_gat_node<<<96, B, 0, stream>>>(nullptr, nullptr, x1, nullptr, nullptr, nullptr, ea,
                                   csr_se, offn, cur, L2, ctrl, C_L2, CAP_L2,
                                   A_n, degf);
  k_gat_edge<<<96, B, 0, stream>>>(nullptr, nullptr, x1, nullptr, nullptr, nullptr, ea,
                                   E3, ctrl, C_E3, CAP_E3, A_e);
  jn = {A_n, w2c, bs_[1], bm_[1], degf, L2, nullptr, x2, nullptr, C_L2, CAP_L2, 1};
  je = {A_e, we_[1], be_[1], nullptr, nullptr, nullptr, E3, nullptr, ea, C_E3, CAP_E3, 1};
  k_gemm_b<<<128, B, 0, stream>>>(jn, je, 2, ctrl);

  // ---- stage 3: masters only, no relu ----
  k_gat_node<<<16, B, 0, stream>>>(nullptr, nullptr, x2, nullptr, nullptr, nullptr, ea,
                                   csr_se, offn, cur, nullptr, ctrl, -1, NGRAPH,
                                   A_n, degf);
  jn = {A_n, w3c, bs_[2], bm_[2], degf, nullptr, nullptr, out, nullptr, -1, NGRAPH, 0};
  jz = {};
  k_gemm_b<<<32, B, 0, stream>>>(jn, jz, 1, ctrl);
}

// Round 8
// 180.064 us; speedup vs baseline: 1.9571x; 1.1938x over previous
//
#include <hip/hip_runtime.h>

typedef unsigned short u16;
typedef unsigned int u32;
typedef unsigned long long u64;

#define N_NODES 100000
#define N_EDGES 600000
#define D 128
#define NPG 1000
#define NGRAPH 100
#define MBW 3136          // mask words (padded) >= ceil(100000/32)

#define CAP_SLOTS 65536   // CSR slots (expected ~29.4k)
#define CAP_L1    16384   // S1 nodes (expected ~4.9k)
#define CAP_L2    4096    // S2 nodes (expected ~700)
#define CAP_E2    16384   // edges into S2 (expected ~4.2k)
#define CAP_E3    4096    // edges into masters (expected ~600)

#define C_SLOT 0
#define C_L1   1
#define C_L2   2
#define C_E2   3
#define C_E3   4

#define NPK (192 * 128)   // packed W elements (u32) per job: 24576

__device__ __forceinline__ float bf2f(u16 u) {
  return __uint_as_float(((u32)u) << 16);
}
__device__ __forceinline__ u16 f2bf(float f) {
  u32 u = __float_as_uint(f);
  u32 r = (u + 0x7FFFu + ((u >> 16) & 1u)) >> 16;  // RNE
  return (u16)r;
}
__device__ __forceinline__ u32 packbf2(float a, float b) {
  return (u32)f2bf(a) | ((u32)f2bf(b) << 16);
}
__device__ __forceinline__ void fma4(float4& acc, float a, const float4 w) {
  acc.x = fmaf(a, w.x, acc.x);
  acc.y = fmaf(a, w.y, acc.y);
  acc.z = fmaf(a, w.z, acc.z);
  acc.w = fmaf(a, w.w, acc.w);
}
__device__ __forceinline__ float4 bf4(uint2 u) {
  return make_float4(bf2f((u16)(u.x & 0xFFFFu)), bf2f((u16)(u.x >> 16)),
                     bf2f((u16)(u.y & 0xFFFFu)), bf2f((u16)(u.y >> 16)));
}
__device__ __forceinline__ void add4(float4& a, const float4 b) {
  a.x += b.x; a.y += b.y; a.z += b.z; a.w += b.w;
}
__device__ __forceinline__ float4 shfl4(float4 v, int lane) {
  return make_float4(__shfl(v.x, lane, 32), __shfl(v.y, lane, 32),
                     __shfl(v.z, lane, 32), __shfl(v.w, lane, 32));
}
__device__ __forceinline__ int mbit(const u32* __restrict__ mb, int n) {
  return (mb[n >> 5] >> (n & 31)) & 1u;
}
__device__ __forceinline__ void mset(u32* __restrict__ mb, int n) {
  atomicOr(&mb[n >> 5], 1u << (n & 31));
}

// ---------------- cone construction (unchanged from R7) ----------------

__global__ __launch_bounds__(256) void k_scan3(const int4* __restrict__ src4,
                                               const int4* __restrict__ dst4,
                                               u32* __restrict__ mb1,
                                               u32* __restrict__ mb2) {
  int i = blockIdx.x * 256 + threadIdx.x;
  if (blockIdx.x == 0 && threadIdx.x < NGRAPH) {
    mset(mb2, threadIdx.x * NPG);
    mset(mb1, threadIdx.x * NPG);
  }
  if (i >= N_EDGES / 4) return;
  int4 d = dst4[i], s = src4[i];
  if (d.x % NPG == 0) { mset(mb2, s.x); mset(mb1, s.x); }
  if (d.y % NPG == 0) { mset(mb2, s.y); mset(mb1, s.y); }
  if (d.z % NPG == 0) { mset(mb2, s.z); mset(mb1, s.z); }
  if (d.w % NPG == 0) { mset(mb2, s.w); mset(mb1, s.w); }
}

__global__ __launch_bounds__(256) void k_scan2(const int4* __restrict__ src4,
                                               const int4* __restrict__ dst4,
                                               const u32* __restrict__ mb2,
                                               u32* __restrict__ mb1) {
  int i = blockIdx.x * 256 + threadIdx.x;
  if (i >= N_EDGES / 4) return;
  int4 d = dst4[i], s = src4[i];
  if (mbit(mb2, d.x)) mset(mb1, s.x);
  if (mbit(mb2, d.y)) mset(mb1, s.y);
  if (mbit(mb2, d.z)) mset(mb1, s.z);
  if (mbit(mb2, d.w)) mset(mb1, s.w);
}

__global__ __launch_bounds__(256) void k_scan1(const int4* __restrict__ dst4,
                                               const u32* __restrict__ mb1,
                                               int* __restrict__ deg) {
  int i = blockIdx.x * 256 + threadIdx.x;
  if (i >= N_EDGES / 4) return;
  int4 d = dst4[i];
  if (mbit(mb1, d.x)) atomicAdd(&deg[d.x], 1);
  if (mbit(mb1, d.y)) atomicAdd(&deg[d.y], 1);
  if (mbit(mb1, d.z)) atomicAdd(&deg[d.z], 1);
  if (mbit(mb1, d.w)) atomicAdd(&deg[d.w], 1);
}

__global__ __launch_bounds__(256) void k_alloc(const u32* __restrict__ mb1,
                                               const u32* __restrict__ mb2,
                                               const int* __restrict__ deg,
                                               int* __restrict__ offn,
                                               int* __restrict__ cur,
                                               int* __restrict__ L1,
                                               int* __restrict__ L2,
                                               int* __restrict__ ctrl) {
  int t = blockIdx.x * 256 + threadIdx.x;
  int lane = threadIdx.x & 63;
  bool inb = t < N_NODES;
  bool mk1 = inb && mbit(mb1, t);
  bool mk2 = inb && mbit(mb2, t);

  int v = mk1 ? deg[t] : 0;
  int incl = v;
#pragma unroll
  for (int o = 1; o < 64; o <<= 1) {
    int u = __shfl_up(incl, o, 64);
    if (lane >= o) incl += u;
  }
  int total = __shfl(incl, 63, 64);
  int sbase = 0;
  if (lane == 0 && total > 0) sbase = atomicAdd(&ctrl[C_SLOT], total);
  sbase = __shfl(sbase, 0, 64);
  int myoff = sbase + incl - v;
  if (mk1) { offn[t] = myoff; cur[t] = myoff; }

  u64 bal = __ballot(mk1);
  int pos = __popcll(bal & ((1ull << lane) - 1ull));
  int lbase = 0;
  if (lane == 0 && bal) lbase = atomicAdd(&ctrl[C_L1], __popcll(bal));
  lbase = __shfl(lbase, 0, 64);
  if (mk1 && lbase + pos < CAP_L1) L1[lbase + pos] = t;

  u64 bal2 = __ballot(mk2);
  int pos2 = __popcll(bal2 & ((1ull << lane) - 1ull));
  int lbase2 = 0;
  if (lane == 0 && bal2) lbase2 = atomicAdd(&ctrl[C_L2], __popcll(bal2));
  lbase2 = __shfl(lbase2, 0, 64);
  if (mk2 && lbase2 + pos2 < CAP_L2) L2[lbase2 + pos2] = t;
}

__global__ __launch_bounds__(256) void k_scatter(const int4* __restrict__ src4,
                                                 const int4* __restrict__ dst4,
                                                 const u32* __restrict__ mb1,
                                                 int* __restrict__ cur,
                                                 int2* __restrict__ csr_se,
                                                 int* __restrict__ csr_dst) {
  int i = blockIdx.x * 256 + threadIdx.x;
  if (i >= N_EDGES / 4) return;
  int4 dv = dst4[i], sv = src4[i];
  int ds[4] = {dv.x, dv.y, dv.z, dv.w};
  int ss[4] = {sv.x, sv.y, sv.z, sv.w};
#pragma unroll
  for (int j = 0; j < 4; ++j) {
    int d = ds[j];
    if (!mbit(mb1, d)) continue;
    int p = atomicAdd(&cur[d], 1);
    if (p < CAP_SLOTS) {
      csr_se[p] = make_int2(ss[j], i * 4 + j);
      csr_dst[p] = d;
    }
  }
}

// merged: blocks [0,480): pack 5 weight buffers to bf16 K-pairs;
//         blocks [480,512): build E2/E3 lists
__global__ __launch_bounds__(256) void k_aux(const int2* __restrict__ csr_se,
                                             const int* __restrict__ csr_dst,
                                             const u32* __restrict__ mb2,
                                             int4* __restrict__ E2,
                                             int4* __restrict__ E3,
                                             int* __restrict__ ctrl,
                                             const float* __restrict__ ws1, const float* __restrict__ wm1,
                                             const float* __restrict__ we1,
                                             const float* __restrict__ ws2, const float* __restrict__ wm2,
                                             const float* __restrict__ we2,
                                             const float* __restrict__ ws3, const float* __restrict__ wm3,
                                             u32* __restrict__ w1p, u32* __restrict__ e1p,
                                             u32* __restrict__ w2p, u32* __restrict__ e2p,
                                             u32* __restrict__ w3p) {
  if (blockIdx.x < 480) {  // 480*256 == 5*NPK
    int t = blockIdx.x * 256 + threadIdx.x;
    int buf = t / NPK, elem = t % NPK;
    int k2 = elem >> 7, c = elem & 127;
    int k0 = 2 * k2, k1 = 2 * k2 + 1;
    float a, b;
    u32* dst;
    if (buf == 0) {
      a = k0 < 128 ? ws1[k0 * 128 + c] : wm1[(k0 - 128) * 128 + c];
      b = k1 < 128 ? ws1[k1 * 128 + c] : wm1[(k1 - 128) * 128 + c];
      dst = w1p;
    } else if (buf == 1) {
      a = we1[k0 * 128 + c]; b = we1[k1 * 128 + c]; dst = e1p;
    } else if (buf == 2) {
      a = k0 < 128 ? ws2[k0 * 128 + c] : wm2[(k0 - 128) * 128 + c];
      b = k1 < 128 ? ws2[k1 * 128 + c] : wm2[(k1 - 128) * 128 + c];
      dst = w2p;
    } else if (buf == 3) {
      a = we2[k0 * 128 + c]; b = we2[k1 * 128 + c]; dst = e2p;
    } else {
      a = k0 < 128 ? ws3[k0 * 128 + c] : wm3[(k0 - 128) * 128 + c];
      b = k1 < 128 ? ws3[k1 * 128 + c] : wm3[(k1 - 128) * 128 + c];
      dst = w3p;
    }
    dst[elem] = packbf2(a, b);
    return;
  }
  int lb = blockIdx.x - 480;  // 32 list blocks
  int ns = ctrl[C_SLOT];
  if (ns > CAP_SLOTS) ns = CAP_SLOTS;
  int lane = threadIdx.x & 63;
  int total = (ns + 255) & ~255;
  for (int p = lb * 256 + threadIdx.x; p < total; p += 32 * 256) {
    bool inb = p < ns;
    int d = inb ? csr_dst[p] : 0;
    bool e2 = inb && mbit(mb2, d);
    bool e3 = inb && (d % NPG == 0);
    int2 se = (e2 || e3) ? csr_se[p] : make_int2(0, 0);
    u64 bal = __ballot(e2);
    if (bal) {
      int base = 0;
      if (lane == 0) base = atomicAdd(&ctrl[C_E2], __popcll(bal));
      base = __shfl(base, 0, 64);
      int pos = __popcll(bal & ((1ull << lane) - 1ull));
      if (e2 && base + pos < CAP_E2) E2[base + pos] = make_int4(p, se.x, d, se.y);
    }
    u64 bal3 = __ballot(e3);
    if (bal3) {
      int base = 0;
      if (lane == 0) base = atomicAdd(&ctrl[C_E3], __popcll(bal3));
      base = __shfl(base, 0, 64);
      int pos = __popcll(bal3 & ((1ull << lane) - 1ull));
      if (e3 && base + pos < CAP_E3) E3[base + pos] = make_int4(p, se.x, d, se.y);
    }
  }
}

// ---------------- gathers: dense A rows [x | sx | se] in bf16, K=384 --------

__device__ __forceinline__ void store_bf16_seg(u16* Arow, int seg, int q, float4 v) {
  ((uint2*)Arow)[seg * 32 + q] = make_uint2(packbf2(v.x, v.y), packbf2(v.z, v.w));
}

__global__ __launch_bounds__(256) void k_gat_node(const int* __restrict__ tok,
                                                  const float* __restrict__ emb,
                                                  const float* __restrict__ xin,
                                                  const float* __restrict__ attr,
                                                  const float* __restrict__ wproj,
                                                  const float* __restrict__ bproj,
                                                  const u16* __restrict__ ea,
                                                  const int2* __restrict__ csr_se,
                                                  const int* __restrict__ offn,
                                                  const int* __restrict__ cur,
                                                  const int* __restrict__ L,
                                                  const int* __restrict__ ctrl, int slot, int cap,
                                                  u16* __restrict__ A,
                                                  float* __restrict__ degf) {
  int n_ = L ? ctrl[slot] : NGRAPH;
  if (n_ > cap) n_ = cap;
  int sub = threadIdx.x >> 5, q = threadIdx.x & 31;
  for (int i = blockIdx.x * 8 + sub; i < n_; i += gridDim.x * 8) {
    int n = L ? L[i] : i * NPG;
    int o = offn[n], end = cur[n];
    float dgf = (float)(end - o);
    float4 sx = make_float4(0.f, 0.f, 0.f, 0.f);
    float4 se = make_float4(0.f, 0.f, 0.f, 0.f);
    float4 xn;
    if (tok) {
      float4 sa = make_float4(0.f, 0.f, 0.f, 0.f);
      for (int p = o; p < end; ++p) {
        int2 se2 = csr_se[p];
        add4(sx, ((const float4*)(emb + (size_t)tok[se2.x] * D))[q]);
        add4(sa, ((const float4*)(attr + (size_t)se2.y * 16))[q & 3]);
      }
      float4 bp = ((const float4*)bproj)[q];
      se = make_float4(bp.x * dgf, bp.y * dgf, bp.z * dgf, bp.w * dgf);
      const float4* wp = (const float4*)wproj;
#pragma unroll
      for (int k4 = 0; k4 < 4; ++k4) {
        float4 xv = shfl4(sa, k4);
        fma4(se, xv.x, wp[(k4 * 4 + 0) * 32 + q]);
        fma4(se, xv.y, wp[(k4 * 4 + 1) * 32 + q]);
        fma4(se, xv.z, wp[(k4 * 4 + 2) * 32 + q]);
        fma4(se, xv.w, wp[(k4 * 4 + 3) * 32 + q]);
      }
      xn = ((const float4*)(emb + (size_t)tok[n] * D))[q];
    } else {
      for (int p = o; p < end; ++p) {
        int s = csr_se[p].x;
        add4(sx, ((const float4*)(xin + (size_t)s * D))[q]);
        add4(se, bf4(((const uint2*)(ea + (size_t)p * D))[q]));
      }
      xn = ((const float4*)(xin + (size_t)n * D))[q];
    }
    u16* Ar = A + (size_t)i * 384;
    store_bf16_seg(Ar, 0, q, xn);
    store_bf16_seg(Ar, 1, q, sx);
    store_bf16_seg(Ar, 2, q, se);
    if (q == 0) degf[i] = dgf;
  }
}

__global__ __launch_bounds__(256) void k_gat_edge(const int* __restrict__ tok,
                                                  const float* __restrict__ emb,
                                                  const float* __restrict__ xin,
                                                  const float* __restrict__ attr,
                                                  const float* __restrict__ wproj,
                                                  const float* __restrict__ bproj,
                                                  const u16* __restrict__ ea,
                                                  const int4* __restrict__ EL,
                                                  const int* __restrict__ ctrl, int slot, int cap,
                                                  u16* __restrict__ A) {
  int n_ = ctrl[slot];
  if (n_ > cap) n_ = cap;
  int sub = threadIdx.x >> 5, q = threadIdx.x & 31;
  for (int i = blockIdx.x * 8 + sub; i < n_; i += gridDim.x * 8) {
    int4 t = EL[i];
    int p = t.x, s = t.y, d = t.z, e = t.w;
    float4 xd, xs, ev;
    if (tok) {
      xd = ((const float4*)(emb + (size_t)tok[d] * D))[q];
      xs = ((const float4*)(emb + (size_t)tok[s] * D))[q];
      float4 av = ((const float4*)(attr + (size_t)e * 16))[q & 3];
      ev = ((const float4*)bproj)[q];
      const float4* wp = (const float4*)wproj;
#pragma unroll
      for (int k4 = 0; k4 < 4; ++k4) {
        float4 xv = shfl4(av, k4);
        fma4(ev, xv.x, wp[(k4 * 4 + 0) * 32 + q]);
        fma4(ev, xv.y, wp[(k4 * 4 + 1) * 32 + q]);
        fma4(ev, xv.z, wp[(k4 * 4 + 2) * 32 + q]);
        fma4(ev, xv.w, wp[(k4 * 4 + 3) * 32 + q]);
      }
    } else {
      xd = ((const float4*)(xin + (size_t)d * D))[q];
      xs = ((const float4*)(xin + (size_t)s * D))[q];
      ev = bf4(((const uint2*)(ea + (size_t)p * D))[q]);
    }
    u16* Ar = A + (size_t)i * 384;
    store_bf16_seg(Ar, 0, q, xd);
    store_bf16_seg(Ar, 1, q, xs);
    store_bf16_seg(Ar, 2, q, ev);
  }
}

// ---------------- W-resident GEMM ----------------
// C[M][128] = A[M][384] @ W + epilogue, A/W bf16, acc f32.
// Block = one (job, 64-col half): stages its 48 KB W-half to LDS ONCE, then
// grid-strides over 16-row tiles staging 12 KB bf16 A-tiles. LDS 60 KB ->
// 2 blocks/CU. Wave wv owns rows 4wv..4wv+3; lane q (0..63) owns col half*64+q.

struct GJob {
  const u16* A;
  const u32* W;        // packed bf16 K-pairs [192][128]
  const float* bias;
  const float* bm;     // null for edge jobs
  const float* degf;   // null for edge jobs
  const int* L;        // node list or null (row index direct)
  const int4* EL;      // edge list (bf16 out slot) or null
  float* outf;
  u16* outb;
  int slot;            // ctrl slot for M, or -1 -> NGRAPH
  int cap;
  int relu;
};

#define ASF(x) __uint_as_float(x)

__global__ __launch_bounds__(256) void k_gemm_b(GJob J0, GJob J1, int njobs,
                                                const int* __restrict__ ctrl) {
  __shared__ uint4 Wl4[3072];   // 48 KB: u32 layout [k2][64] for this col-half
  __shared__ uint4 Al4[768];    // 12 KB: 16 rows x 384 bf16
  const u32* Wlds = (const u32*)Wl4;
  int q = threadIdx.x & 63, wv = threadIdx.x >> 6;

  int job, half, lid, cnt;
  if (njobs == 2) {
    job = (blockIdx.x & 2) >> 1; half = blockIdx.x & 1;
    lid = blockIdx.x >> 2; cnt = gridDim.x >> 2;
  } else {
    job = 0; half = blockIdx.x & 1;
    lid = blockIdx.x >> 1; cnt = gridDim.x >> 1;
  }
  const GJob& J = job ? J1 : J0;
  int M = J.slot < 0 ? NGRAPH : ctrl[J.slot];
  if (M > J.cap) M = J.cap;
  int nt = (M + 15) >> 4;

  // stage W-half once: u32 idx k2*64+c  <-  global u32 idx k2*128 + half*64 + c
#pragma unroll
  for (int u = 0; u < 12; ++u) {
    int idx = threadIdx.x + u * 256;        // 0..3071 uint4
    int k2 = idx >> 4, c4 = idx & 15;
    Wl4[idx] = ((const uint4*)J.W)[k2 * 32 + half * 16 + c4];
  }

  float bias = J.bias[half * 64 + q];
  float bmv = J.degf ? J.bm[half * 64 + q] : 0.f;

  for (int t = lid; t < nt; t += cnt) {
    __syncthreads();  // W ready / previous tile's A reads done
#pragma unroll
    for (int u = 0; u < 3; ++u) {
      int idx = threadIdx.x + u * 256;      // 0..767 uint4
      int row = idx / 48, c8 = idx % 48;    // 48 uint4 per 768B row
      int gr = t * 16 + row;
      if (gr > M - 1) gr = M - 1;
      Al4[idx] = ((const uint4*)(J.A + (size_t)gr * 384))[c8];
    }
    __syncthreads();

    const uint2* A0 = (const uint2*)Al4 + (wv * 4 + 0) * 96;
    const uint2* A1 = (const uint2*)Al4 + (wv * 4 + 1) * 96;
    const uint2* A2 = (const uint2*)Al4 + (wv * 4 + 2) * 96;
    const uint2* A3 = (const uint2*)Al4 + (wv * 4 + 3) * 96;
    float acc0 = bias, acc1 = bias, acc2 = bias, acc3 = bias;
#pragma unroll 8
    for (int k4 = 0; k4 < 96; ++k4) {
      u32 wA = Wlds[(k4 * 2) * 64 + q];      // K 4k4, 4k4+1 (lo,hi)
      u32 wB = Wlds[(k4 * 2 + 1) * 64 + q];  // K 4k4+2, 4k4+3
      float wk0 = ASF(wA << 16), wk1 = ASF(wA & 0xffff0000u);
      float wk2 = ASF(wB << 16), wk3 = ASF(wB & 0xffff0000u);
      uint2 a;
      a = A0[k4];
      acc0 = fmaf(ASF(a.x << 16), wk0, acc0);
      acc0 = fmaf(ASF(a.x & 0xffff0000u), wk1, acc0);
      acc0 = fmaf(ASF(a.y << 16), wk2, acc0);
      acc0 = fmaf(ASF(a.y & 0xffff0000u), wk3, acc0);
      a = A1[k4];
      acc1 = fmaf(ASF(a.x << 16), wk0, acc1);
      acc1 = fmaf(ASF(a.x & 0xffff0000u), wk1, acc1);
      acc1 = fmaf(ASF(a.y << 16), wk2, acc1);
      acc1 = fmaf(ASF(a.y & 0xffff0000u), wk3, acc1);
      a = A2[k4];
      acc2 = fmaf(ASF(a.x << 16), wk0, acc2);
      acc2 = fmaf(ASF(a.x & 0xffff0000u), wk1, acc2);
      acc2 = fmaf(ASF(a.y << 16), wk2, acc2);
      acc2 = fmaf(ASF(a.y & 0xffff0000u), wk3, acc2);
      a = A3[k4];
      acc3 = fmaf(ASF(a.x << 16), wk0, acc3);
      acc3 = fmaf(ASF(a.x & 0xffff0000u), wk1, acc3);
      acc3 = fmaf(ASF(a.y << 16), wk2, acc3);
      acc3 = fmaf(ASF(a.y & 0xffff0000u), wk3, acc3);
    }

    float accs[4] = {acc0, acc1, acc2, acc3};
#pragma unroll
    for (int r = 0; r < 4; ++r) {
      int row = t * 16 + wv * 4 + r;
      if (row < M) {
        float a = accs[r];
        if (J.degf) a = fmaf(J.degf[row], bmv, a);
        if (J.relu) a = fmaxf(a, 0.f);
        if (J.outb) {
          int p = J.EL[row].x;
          J.outb[(size_t)p * D + half * 64 + q] = f2bf(a);
        } else {
          int idx = J.L ? J.L[row] : row;
          J.outf[(size_t)idx * D + half * 64 + q] = a;
        }
      }
    }
  }
}

extern "C" void kernel_launch(void* const* d_in, const int* in_sizes, int n_in,
                              void* d_out, int out_size, void* d_ws, size_t ws_size,
                              hipStream_t stream) {
  const int* tok = (const int*)d_in[0];
  const int* eidx = (const int*)d_in[1];
  const int4* src4 = (const int4*)eidx;
  const int4* dst4 = (const int4*)(eidx + N_EDGES);
  const float* attr = (const float*)d_in[2];
  const float* emb = (const float*)d_in[4];
  const float* w_proj = (const float*)d_in[5];
  const float* b_proj = (const float*)d_in[6];
  const float *ws_[3], *bs_[3], *wm_[3], *bm_[3], *we_[3], *be_[3];
  for (int i = 0; i < 3; ++i) {
    ws_[i] = (const float*)d_in[7 + 6 * i];
    bs_[i] = (const float*)d_in[8 + 6 * i];
    wm_[i] = (const float*)d_in[9 + 6 * i];
    bm_[i] = (const float*)d_in[10 + 6 * i];
    we_[i] = (const float*)d_in[11 + 6 * i];
    be_[i] = (const float*)d_in[12 + 6 * i];
  }
  float* out = (float*)d_out;

  // ---- workspace ----
  char* base = (char*)d_ws;
  size_t o = 0;
  int* ctrl = (int*)(base + o); o += 256;
  u32* mb1 = (u32*)(base + o); o += MBW * 4;
  u32* mb2 = (u32*)(base + o); o += MBW * 4;
  int* deg = (int*)(base + o); o += (size_t)N_NODES * 4;
  size_t zero_bytes = o;  // ctrl + masks + deg zeroed each call
  int* offn = (int*)(base + o); o += (size_t)N_NODES * 4;
  int* cur = (int*)(base + o); o += (size_t)N_NODES * 4;
  int2* csr_se = (int2*)(base + o); o += (size_t)CAP_SLOTS * 8;
  int* csr_dst = (int*)(base + o); o += (size_t)CAP_SLOTS * 4;
  o = (o + 15) & ~(size_t)15;
  int4* E2 = (int4*)(base + o); o += (size_t)CAP_E2 * 16;
  int4* E3 = (int4*)(base + o); o += (size_t)CAP_E3 * 16;
  int* L1 = (int*)(base + o); o += (size_t)CAP_L1 * 4;
  int* L2 = (int*)(base + o); o += (size_t)CAP_L2 * 4;
  float* degf = (float*)(base + o); o += (size_t)CAP_L1 * 4;
  o = (o + 15) & ~(size_t)15;
  u32* w1p = (u32*)(base + o); o += (size_t)NPK * 4;
  u32* e1p = (u32*)(base + o); o += (size_t)NPK * 4;
  u32* w2p = (u32*)(base + o); o += (size_t)NPK * 4;
  u32* e2p = (u32*)(base + o); o += (size_t)NPK * 4;
  u32* w3p = (u32*)(base + o); o += (size_t)NPK * 4;
  o = (o + 511) & ~(size_t)511;
  u16* A_n = (u16*)(base + o); o += (size_t)CAP_L1 * 384 * 2;   // 12.6 MB
  u16* A_e = (u16*)(base + o); o += (size_t)CAP_E2 * 384 * 2;   // 12.6 MB
  float* x1 = (float*)(base + o); o += (size_t)N_NODES * D * 4; // 51 MB
  float* x2 = (float*)(base + o); o += (size_t)N_NODES * D * 4; // 51 MB
  u16* ea = (u16*)(base + o); o += (size_t)CAP_SLOTS * D * 2;   // 16 MB

  hipMemsetAsync(d_ws, 0, zero_bytes, stream);

  dim3 B(256);
  const int EG4 = (N_EDGES / 4 + 255) / 256;  // 586
  const int NG = (N_NODES + 255) / 256;       // 391

  // cone + CSR
  k_scan3<<<EG4, B, 0, stream>>>(src4, dst4, mb1, mb2);
  k_scan2<<<EG4, B, 0, stream>>>(src4, dst4, mb2, mb1);
  k_scan1<<<EG4, B, 0, stream>>>(dst4, mb1, deg);
  k_alloc<<<NG, B, 0, stream>>>(mb1, mb2, deg, offn, cur, L1, L2, ctrl);
  k_scatter<<<EG4, B, 0, stream>>>(src4, dst4, mb1, cur, csr_se, csr_dst);
  k_aux<<<512, B, 0, stream>>>(csr_se, csr_dst, mb2, E2, E3, ctrl,
                               ws_[0], wm_[0], we_[0],
                               ws_[1], wm_[1], we_[1],
                               ws_[2], wm_[2],
                               w1p, e1p, w2p, e2p, w3p);

  GJob jn, je, jz;
  // ---- stage 1 ----
  k_gat_node<<<640, B, 0, stream>>>(tok, emb, nullptr, attr, w_proj, b_proj, ea,
                                    csr_se, offn, cur, L1, ctrl, C_L1, CAP_L1,
                                    A_n, degf);
  k_gat_edge<<<640, B, 0, stream>>>(tok, emb, nullptr, attr, w_proj, b_proj, ea,
                                    E2, ctrl, C_E2, CAP_E2, A_e);
  jn = {A_n, w1p, bs_[0], bm_[0], degf, L1, nullptr, x1, nullptr, C_L1, CAP_L1, 1};
  je = {A_e, e1p, be_[0], nullptr, nullptr, nullptr, E2, nullptr, ea, C_E2, CAP_E2, 1};
  k_gemm_b<<<448, B, 0, stream>>>(jn, je, 2, ctrl);

  // ---- stage 2 ----
  k_gat_node<<<96, B, 0, stream>>>(nullptr, nullptr, x1, nullptr, nullptr, nullptr, ea,
                                   csr_se, offn, cur, L2, ctrl, C_L2, CAP_L2,
                                   A_n, degf);
  k_gat_edge<<<96, B, 0, stream>>>(nullptr, nullptr, x1, nullptr, nullptr, nullptr, ea,
                                   E3, ctrl, C_E3, CAP_E3, A_e);
  jn = {A_n, w2p, bs_[1], bm_[1], degf, L2, nullptr, x2, nullptr, C_L2, CAP_L2, 1};
  je = {A_e, e2p, be_[1], nullptr, nullptr, nullptr, E3, nullptr, ea, C_E3, CAP_E3, 1};
  k_gemm_b<<<128, B, 0, stream>>>(jn, je, 2, ctrl);

  // ---- stage 3: masters only, no relu ----
  k_gat_node<<<16, B, 0, stream>>>(nullptr, nullptr, x2, nullptr, nullptr, nullptr, ea,
                                   csr_se, offn, cur, nullptr, ctrl, -1, NGRAPH,
                                   A_n, degf);
  jn = {A_n, w3p, bs_[2], bm_[2], degf, nullptr, nullptr, out, nullptr, -1, NGRAPH, 0};
  jz = {};
  k_gemm_b<<<16, B, 0, stream>>>(jn, jz, 1, ctrl);
}

// Round 9
// 132.772 us; speedup vs baseline: 2.6543x; 1.3562x over previous
//
#include <hip/hip_runtime.h>

typedef unsigned short u16;
typedef unsigned int u32;
typedef unsigned long long u64;

#define N_NODES 100000
#define N_EDGES 600000
#define D 128
#define NPG 1000
#define NGRAPH 100
#define MBW 3136          // mask words (padded) >= ceil(100000/32)

#define CAP_SLOTS 65536   // CSR slots (expected ~29.4k)
#define CAP_L1    16384   // S1 nodes (expected ~4.9k)
#define CAP_L2    4096    // S2 nodes (expected ~700)
#define CAP_E2    16384   // edges into S2 (expected ~4.2k)
#define CAP_E3    4096    // edges into masters (expected ~600)

#define C_SLOT 0
#define C_L1   1
#define C_L2   2
#define C_E2   3
#define C_E3   4
#define C64    8          // int-index of packed u64 alloc counter (byte 32, 8-aligned)

#define NPK (192 * 128)   // packed W elements (u32) per job: 24576

__device__ __forceinline__ float bf2f(u16 u) {
  return __uint_as_float(((u32)u) << 16);
}
__device__ __forceinline__ u16 f2bf(float f) {
  u32 u = __float_as_uint(f);
  u32 r = (u + 0x7FFFu + ((u >> 16) & 1u)) >> 16;  // RNE
  return (u16)r;
}
__device__ __forceinline__ u32 packbf2(float a, float b) {
  return (u32)f2bf(a) | ((u32)f2bf(b) << 16);
}
__device__ __forceinline__ void fma4(float4& acc, float a, const float4 w) {
  acc.x = fmaf(a, w.x, acc.x);
  acc.y = fmaf(a, w.y, acc.y);
  acc.z = fmaf(a, w.z, acc.z);
  acc.w = fmaf(a, w.w, acc.w);
}
__device__ __forceinline__ float4 bf4(uint2 u) {
  return make_float4(bf2f((u16)(u.x & 0xFFFFu)), bf2f((u16)(u.x >> 16)),
                     bf2f((u16)(u.y & 0xFFFFu)), bf2f((u16)(u.y >> 16)));
}
__device__ __forceinline__ void add4(float4& a, const float4 b) {
  a.x += b.x; a.y += b.y; a.z += b.z; a.w += b.w;
}
__device__ __forceinline__ float4 shfl4(float4 v, int lane) {
  return make_float4(__shfl(v.x, lane, 32), __shfl(v.y, lane, 32),
                     __shfl(v.z, lane, 32), __shfl(v.w, lane, 32));
}
__device__ __forceinline__ int mbit(const u32* __restrict__ mb, int n) {
  return (mb[n >> 5] >> (n & 31)) & 1u;
}
__device__ __forceinline__ void mset(u32* __restrict__ mb, int n) {
  atomicOr(&mb[n >> 5], 1u << (n & 31));
}

// ---------------- cone construction ----------------

__global__ __launch_bounds__(256) void k_scan3(const int4* __restrict__ src4,
                                               const int4* __restrict__ dst4,
                                               u32* __restrict__ mb1,
                                               u32* __restrict__ mb2) {
  int i = blockIdx.x * 256 + threadIdx.x;
  if (blockIdx.x == 0 && threadIdx.x < NGRAPH) {
    mset(mb2, threadIdx.x * NPG);
    mset(mb1, threadIdx.x * NPG);
  }
  if (i >= N_EDGES / 4) return;
  int4 d = dst4[i], s = src4[i];
  if (d.x % NPG == 0) { mset(mb2, s.x); mset(mb1, s.x); }
  if (d.y % NPG == 0) { mset(mb2, s.y); mset(mb1, s.y); }
  if (d.z % NPG == 0) { mset(mb2, s.z); mset(mb1, s.z); }
  if (d.w % NPG == 0) { mset(mb2, s.w); mset(mb1, s.w); }
}

__global__ __launch_bounds__(256) void k_scan2(const int4* __restrict__ src4,
                                               const int4* __restrict__ dst4,
                                               const u32* __restrict__ mb2,
                                               u32* __restrict__ mb1) {
  int i = blockIdx.x * 256 + threadIdx.x;
  if (i >= N_EDGES / 4) return;
  int4 d = dst4[i], s = src4[i];
  if (mbit(mb2, d.x)) mset(mb1, s.x);
  if (mbit(mb2, d.y)) mset(mb1, s.y);
  if (mbit(mb2, d.z)) mset(mb1, s.z);
  if (mbit(mb2, d.w)) mset(mb1, s.w);
}

__global__ __launch_bounds__(256) void k_scan1(const int4* __restrict__ dst4,
                                               const u32* __restrict__ mb1,
                                               int* __restrict__ deg) {
  int i = blockIdx.x * 256 + threadIdx.x;
  if (i >= N_EDGES / 4) return;
  int4 d = dst4[i];
  if (mbit(mb1, d.x)) atomicAdd(&deg[d.x], 1);
  if (mbit(mb1, d.y)) atomicAdd(&deg[d.y], 1);
  if (mbit(mb1, d.z)) atomicAdd(&deg[d.z], 1);
  if (mbit(mb1, d.w)) atomicAdd(&deg[d.w], 1);
}

// CSR allocation: block-wide scan, ONE packed-u64 atomic per block (98 total).
// Packed fields: slot [0,24) | L1 [24,44) | L2 [44,64).
__global__ __launch_bounds__(1024) void k_alloc(const u32* __restrict__ mb1,
                                                const u32* __restrict__ mb2,
                                                const int* __restrict__ deg,
                                                int* __restrict__ offn,
                                                int* __restrict__ cur,
                                                int* __restrict__ L1,
                                                int* __restrict__ L2,
                                                int* __restrict__ ctrl) {
  __shared__ int wsum[16], wcnt1[16], wcnt2[16];
  __shared__ int bbase[3];
  int tid = threadIdx.x, lane = tid & 63, wid = tid >> 6;
  int t = blockIdx.x * 1024 + tid;
  bool inb = t < N_NODES;
  bool mk1 = inb && mbit(mb1, t);
  bool mk2 = inb && mbit(mb2, t);

  int v = mk1 ? deg[t] : 0;
  int incl = v;
#pragma unroll
  for (int o = 1; o < 64; o <<= 1) {
    int u = __shfl_up(incl, o, 64);
    if (lane >= o) incl += u;
  }
  u64 bal1 = __ballot(mk1);
  u64 bal2 = __ballot(mk2);
  if (lane == 63) {
    wsum[wid] = incl;
    wcnt1[wid] = __popcll(bal1);
    wcnt2[wid] = __popcll(bal2);
  }
  __syncthreads();
  if (wid == 0 && lane < 16) {
    int s0 = wsum[lane], c1 = wcnt1[lane], c2 = wcnt2[lane];
    int si = s0, c1i = c1, c2i = c2;
#pragma unroll
    for (int o = 1; o < 16; o <<= 1) {
      int a = __shfl_up(si, o, 64);
      int b = __shfl_up(c1i, o, 64);
      int c = __shfl_up(c2i, o, 64);
      if (lane >= o) { si += a; c1i += b; c2i += c; }
    }
    if (lane == 15) {
      u64 pk = (u64)si | ((u64)c1i << 24) | ((u64)c2i << 44);
      u64 old = atomicAdd((u64*)(ctrl + C64), pk);
      bbase[0] = (int)(old & 0xFFFFFF);
      bbase[1] = (int)((old >> 24) & 0xFFFFF);
      bbase[2] = (int)(old >> 44);
    }
    wsum[lane] = si - s0;   // exclusive wave bases
    wcnt1[lane] = c1i - c1;
    wcnt2[lane] = c2i - c2;
  }
  __syncthreads();
  if (mk1) {
    int myoff = bbase[0] + wsum[wid] + incl - v;
    offn[t] = myoff;
    cur[t] = myoff;
    int pos1 = bbase[1] + wcnt1[wid] + __popcll(bal1 & ((1ull << lane) - 1ull));
    if (pos1 < CAP_L1) L1[pos1] = t;
  }
  if (mk2) {
    int pos2 = bbase[2] + wcnt2[wid] + __popcll(bal2 & ((1ull << lane) - 1ull));
    if (pos2 < CAP_L2) L2[pos2] = t;
  }
}

// scatter edges into CSR (distributed cur atomics); block 0 unpacks alloc totals
__global__ __launch_bounds__(256) void k_scatter(const int4* __restrict__ src4,
                                                 const int4* __restrict__ dst4,
                                                 const u32* __restrict__ mb1,
                                                 int* __restrict__ cur,
                                                 int2* __restrict__ csr_se,
                                                 int* __restrict__ csr_dst,
                                                 int* __restrict__ ctrl) {
  if (blockIdx.x == 0 && threadIdx.x == 0) {
    u64 pk = *(const u64*)(ctrl + C64);
    ctrl[C_SLOT] = (int)(pk & 0xFFFFFF);
    ctrl[C_L1] = (int)((pk >> 24) & 0xFFFFF);
    ctrl[C_L2] = (int)(pk >> 44);
  }
  int i = blockIdx.x * 256 + threadIdx.x;
  if (i >= N_EDGES / 4) return;
  int4 dv = dst4[i], sv = src4[i];
  int ds[4] = {dv.x, dv.y, dv.z, dv.w};
  int ss[4] = {sv.x, sv.y, sv.z, sv.w};
#pragma unroll
  for (int j = 0; j < 4; ++j) {
    int d = ds[j];
    if (!mbit(mb1, d)) continue;
    int p = atomicAdd(&cur[d], 1);
    if (p < CAP_SLOTS) {
      csr_se[p] = make_int2(ss[j], i * 4 + j);
      csr_dst[p] = d;
    }
  }
}

// merged: blocks [0,480): pack 5 weight buffers to bf16 K-pairs;
//         blocks [480,512): build E2/E3 lists
__global__ __launch_bounds__(256) void k_aux(const int2* __restrict__ csr_se,
                                             const int* __restrict__ csr_dst,
                                             const u32* __restrict__ mb2,
                                             int4* __restrict__ E2,
                                             int4* __restrict__ E3,
                                             int* __restrict__ ctrl,
                                             const float* __restrict__ ws1, const float* __restrict__ wm1,
                                             const float* __restrict__ we1,
                                             const float* __restrict__ ws2, const float* __restrict__ wm2,
                                             const float* __restrict__ we2,
                                             const float* __restrict__ ws3, const float* __restrict__ wm3,
                                             u32* __restrict__ w1p, u32* __restrict__ e1p,
                                             u32* __restrict__ w2p, u32* __restrict__ e2p,
                                             u32* __restrict__ w3p) {
  if (blockIdx.x < 480) {  // 480*256 == 5*NPK
    int t = blockIdx.x * 256 + threadIdx.x;
    int buf = t / NPK, elem = t % NPK;
    int k2 = elem >> 7, c = elem & 127;
    int k0 = 2 * k2, k1 = 2 * k2 + 1;
    float a, b;
    u32* dst;
    if (buf == 0) {
      a = k0 < 128 ? ws1[k0 * 128 + c] : wm1[(k0 - 128) * 128 + c];
      b = k1 < 128 ? ws1[k1 * 128 + c] : wm1[(k1 - 128) * 128 + c];
      dst = w1p;
    } else if (buf == 1) {
      a = we1[k0 * 128 + c]; b = we1[k1 * 128 + c]; dst = e1p;
    } else if (buf == 2) {
      a = k0 < 128 ? ws2[k0 * 128 + c] : wm2[(k0 - 128) * 128 + c];
      b = k1 < 128 ? ws2[k1 * 128 + c] : wm2[(k1 - 128) * 128 + c];
      dst = w2p;
    } else if (buf == 3) {
      a = we2[k0 * 128 + c]; b = we2[k1 * 128 + c]; dst = e2p;
    } else {
      a = k0 < 128 ? ws3[k0 * 128 + c] : wm3[(k0 - 128) * 128 + c];
      b = k1 < 128 ? ws3[k1 * 128 + c] : wm3[(k1 - 128) * 128 + c];
      dst = w3p;
    }
    dst[elem] = packbf2(a, b);
    return;
  }
  int lb = blockIdx.x - 480;  // 32 list blocks
  int ns = ctrl[C_SLOT];
  if (ns > CAP_SLOTS) ns = CAP_SLOTS;
  int lane = threadIdx.x & 63;
  int total = (ns + 255) & ~255;
  for (int p = lb * 256 + threadIdx.x; p < total; p += 32 * 256) {
    bool inb = p < ns;
    int d = inb ? csr_dst[p] : 0;
    bool e2 = inb && mbit(mb2, d);
    bool e3 = inb && (d % NPG == 0);
    int2 se = (e2 || e3) ? csr_se[p] : make_int2(0, 0);
    u64 bal = __ballot(e2);
    if (bal) {
      int base = 0;
      if (lane == 0) base = atomicAdd(&ctrl[C_E2], __popcll(bal));
      base = __shfl(base, 0, 64);
      int pos = __popcll(bal & ((1ull << lane) - 1ull));
      if (e2 && base + pos < CAP_E2) E2[base + pos] = make_int4(p, se.x, d, se.y);
    }
    u64 bal3 = __ballot(e3);
    if (bal3) {
      int base = 0;
      if (lane == 0) base = atomicAdd(&ctrl[C_E3], __popcll(bal3));
      base = __shfl(base, 0, 64);
      int pos = __popcll(bal3 & ((1ull << lane) - 1ull));
      if (e3 && base + pos < CAP_E3) E3[base + pos] = make_int4(p, se.x, d, se.y);
    }
  }
}

// ---------------- merged gather: blocks [0,split) node rows, [split,..) edge rows

__device__ __forceinline__ void store_bf16_seg(u16* Arow, int seg, int q, float4 v) {
  ((uint2*)Arow)[seg * 32 + q] = make_uint2(packbf2(v.x, v.y), packbf2(v.z, v.w));
}

__global__ __launch_bounds__(256) void k_gather(const int* __restrict__ tok,
                                                const float* __restrict__ emb,
                                                const float* __restrict__ xin,
                                                const float* __restrict__ attr,
                                                const float* __restrict__ wproj,
                                                const float* __restrict__ bproj,
                                                const u16* __restrict__ ea,
                                                const int2* __restrict__ csr_se,
                                                const int* __restrict__ offn,
                                                const int* __restrict__ cur,
                                                const int* __restrict__ L,
                                                const int4* __restrict__ EL,
                                                const int* __restrict__ ctrl,
                                                int slotN, int capN, int slotE, int capE,
                                                int split,
                                                u16* __restrict__ An,
                                                u16* __restrict__ Ae,
                                                float* __restrict__ degf) {
  int sub = threadIdx.x >> 5, q = threadIdx.x & 31;
  if (blockIdx.x < split) {
    // ---- node gather ----
    int n_ = L ? ctrl[slotN] : NGRAPH;
    if (n_ > capN) n_ = capN;
    for (int i = blockIdx.x * 8 + sub; i < n_; i += split * 8) {
      int n = L ? L[i] : i * NPG;
      int o = offn[n], end = cur[n];
      float dgf = (float)(end - o);
      float4 sx = make_float4(0.f, 0.f, 0.f, 0.f);
      float4 se = make_float4(0.f, 0.f, 0.f, 0.f);
      float4 xn;
      if (tok) {
        float4 sa = make_float4(0.f, 0.f, 0.f, 0.f);
        for (int p = o; p < end; ++p) {
          int2 se2 = csr_se[p];
          add4(sx, ((const float4*)(emb + (size_t)tok[se2.x] * D))[q]);
          add4(sa, ((const float4*)(attr + (size_t)se2.y * 16))[q & 3]);
        }
        float4 bp = ((const float4*)bproj)[q];
        se = make_float4(bp.x * dgf, bp.y * dgf, bp.z * dgf, bp.w * dgf);
        const float4* wp = (const float4*)wproj;
#pragma unroll
        for (int k4 = 0; k4 < 4; ++k4) {
          float4 xv = shfl4(sa, k4);
          fma4(se, xv.x, wp[(k4 * 4 + 0) * 32 + q]);
          fma4(se, xv.y, wp[(k4 * 4 + 1) * 32 + q]);
          fma4(se, xv.z, wp[(k4 * 4 + 2) * 32 + q]);
          fma4(se, xv.w, wp[(k4 * 4 + 3) * 32 + q]);
        }
        xn = ((const float4*)(emb + (size_t)tok[n] * D))[q];
      } else {
        for (int p = o; p < end; ++p) {
          int s = csr_se[p].x;
          add4(sx, ((const float4*)(xin + (size_t)s * D))[q]);
          add4(se, bf4(((const uint2*)(ea + (size_t)p * D))[q]));
        }
        xn = ((const float4*)(xin + (size_t)n * D))[q];
      }
      u16* Ar = An + (size_t)i * 384;
      store_bf16_seg(Ar, 0, q, xn);
      store_bf16_seg(Ar, 1, q, sx);
      store_bf16_seg(Ar, 2, q, se);
      if (q == 0) degf[i] = dgf;
    }
  } else {
    // ---- edge gather ----
    if (slotE < 0) return;
    int n_ = ctrl[slotE];
    if (n_ > capE) n_ = capE;
    int eb = gridDim.x - split;
    for (int i = (blockIdx.x - split) * 8 + sub; i < n_; i += eb * 8) {
      int4 t = EL[i];
      int p = t.x, s = t.y, d = t.z, e = t.w;
      float4 xd, xs, ev;
      if (tok) {
        xd = ((const float4*)(emb + (size_t)tok[d] * D))[q];
        xs = ((const float4*)(emb + (size_t)tok[s] * D))[q];
        float4 av = ((const float4*)(attr + (size_t)e * 16))[q & 3];
        ev = ((const float4*)bproj)[q];
        const float4* wp = (const float4*)wproj;
#pragma unroll
        for (int k4 = 0; k4 < 4; ++k4) {
          float4 xv = shfl4(av, k4);
          fma4(ev, xv.x, wp[(k4 * 4 + 0) * 32 + q]);
          fma4(ev, xv.y, wp[(k4 * 4 + 1) * 32 + q]);
          fma4(ev, xv.z, wp[(k4 * 4 + 2) * 32 + q]);
          fma4(ev, xv.w, wp[(k4 * 4 + 3) * 32 + q]);
        }
      } else {
        xd = ((const float4*)(xin + (size_t)d * D))[q];
        xs = ((const float4*)(xin + (size_t)s * D))[q];
        ev = bf4(((const uint2*)(ea + (size_t)p * D))[q]);
      }
      u16* Ar = Ae + (size_t)i * 384;
      store_bf16_seg(Ar, 0, q, xd);
      store_bf16_seg(Ar, 1, q, xs);
      store_bf16_seg(Ar, 2, q, ev);
    }
  }
}

// ---------------- W-resident GEMM (unchanged from R8) ----------------

struct GJob {
  const u16* A;
  const u32* W;        // packed bf16 K-pairs [192][128]
  const float* bias;
  const float* bm;     // null for edge jobs
  const float* degf;   // null for edge jobs
  const int* L;        // node list or null (row index direct)
  const int4* EL;      // edge list (bf16 out slot) or null
  float* outf;
  u16* outb;
  int slot;            // ctrl slot for M, or -1 -> NGRAPH
  int cap;
  int relu;
};

#define ASF(x) __uint_as_float(x)

__global__ __launch_bounds__(256) void k_gemm_b(GJob J0, GJob J1, int njobs,
                                                const int* __restrict__ ctrl) {
  __shared__ uint4 Wl4[3072];   // 48 KB: u32 layout [k2][64] for this col-half
  __shared__ uint4 Al4[768];    // 12 KB: 16 rows x 384 bf16
  const u32* Wlds = (const u32*)Wl4;
  int q = threadIdx.x & 63, wv = threadIdx.x >> 6;

  int job, half, lid, cnt;
  if (njobs == 2) {
    job = (blockIdx.x & 2) >> 1; half = blockIdx.x & 1;
    lid = blockIdx.x >> 2; cnt = gridDim.x >> 2;
  } else {
    job = 0; half = blockIdx.x & 1;
    lid = blockIdx.x >> 1; cnt = gridDim.x >> 1;
  }
  const GJob& J = job ? J1 : J0;
  int M = J.slot < 0 ? NGRAPH : ctrl[J.slot];
  if (M > J.cap) M = J.cap;
  int nt = (M + 15) >> 4;

#pragma unroll
  for (int u = 0; u < 12; ++u) {
    int idx = threadIdx.x + u * 256;        // 0..3071 uint4
    int k2 = idx >> 4, c4 = idx & 15;
    Wl4[idx] = ((const uint4*)J.W)[k2 * 32 + half * 16 + c4];
  }

  float bias = J.bias[half * 64 + q];
  float bmv = J.degf ? J.bm[half * 64 + q] : 0.f;

  for (int t = lid; t < nt; t += cnt) {
    __syncthreads();
#pragma unroll
    for (int u = 0; u < 3; ++u) {
      int idx = threadIdx.x + u * 256;      // 0..767 uint4
      int row = idx / 48, c8 = idx % 48;
      int gr = t * 16 + row;
      if (gr > M - 1) gr = M - 1;
      Al4[idx] = ((const uint4*)(J.A + (size_t)gr * 384))[c8];
    }
    __syncthreads();

    const uint2* A0 = (const uint2*)Al4 + (wv * 4 + 0) * 96;
    const uint2* A1 = (const uint2*)Al4 + (wv * 4 + 1) * 96;
    const uint2* A2 = (const uint2*)Al4 + (wv * 4 + 2) * 96;
    const uint2* A3 = (const uint2*)Al4 + (wv * 4 + 3) * 96;
    float acc0 = bias, acc1 = bias, acc2 = bias, acc3 = bias;
#pragma unroll 8
    for (int k4 = 0; k4 < 96; ++k4) {
      u32 wA = Wlds[(k4 * 2) * 64 + q];
      u32 wB = Wlds[(k4 * 2 + 1) * 64 + q];
      float wk0 = ASF(wA << 16), wk1 = ASF(wA & 0xffff0000u);
      float wk2 = ASF(wB << 16), wk3 = ASF(wB & 0xffff0000u);
      uint2 a;
      a = A0[k4];
      acc0 = fmaf(ASF(a.x << 16), wk0, acc0);
      acc0 = fmaf(ASF(a.x & 0xffff0000u), wk1, acc0);
      acc0 = fmaf(ASF(a.y << 16), wk2, acc0);
      acc0 = fmaf(ASF(a.y & 0xffff0000u), wk3, acc0);
      a = A1[k4];
      acc1 = fmaf(ASF(a.x << 16), wk0, acc1);
      acc1 = fmaf(ASF(a.x & 0xffff0000u), wk1, acc1);
      acc1 = fmaf(ASF(a.y << 16), wk2, acc1);
      acc1 = fmaf(ASF(a.y & 0xffff0000u), wk3, acc1);
      a = A2[k4];
      acc2 = fmaf(ASF(a.x << 16), wk0, acc2);
      acc2 = fmaf(ASF(a.x & 0xffff0000u), wk1, acc2);
      acc2 = fmaf(ASF(a.y << 16), wk2, acc2);
      acc2 = fmaf(ASF(a.y & 0xffff0000u), wk3, acc2);
      a = A3[k4];
      acc3 = fmaf(ASF(a.x << 16), wk0, acc3);
      acc3 = fmaf(ASF(a.x & 0xffff0000u), wk1, acc3);
      acc3 = fmaf(ASF(a.y << 16), wk2, acc3);
      acc3 = fmaf(ASF(a.y & 0xffff0000u), wk3, acc3);
    }

    float accs[4] = {acc0, acc1, acc2, acc3};
#pragma unroll
    for (int r = 0; r < 4; ++r) {
      int row = t * 16 + wv * 4 + r;
      if (row < M) {
        float a = accs[r];
        if (J.degf) a = fmaf(J.degf[row], bmv, a);
        if (J.relu) a = fmaxf(a, 0.f);
        if (J.outb) {
          int p = J.EL[row].x;
          J.outb[(size_t)p * D + half * 64 + q] = f2bf(a);
        } else {
          int idx = J.L ? J.L[row] : row;
          J.outf[(size_t)idx * D + half * 64 + q] = a;
        }
      }
    }
  }
}

extern "C" void kernel_launch(void* const* d_in, const int* in_sizes, int n_in,
                              void* d_out, int out_size, void* d_ws, size_t ws_size,
                              hipStream_t stream) {
  const int* tok = (const int*)d_in[0];
  const int* eidx = (const int*)d_in[1];
  const int4* src4 = (const int4*)eidx;
  const int4* dst4 = (const int4*)(eidx + N_EDGES);
  const float* attr = (const float*)d_in[2];
  const float* emb = (const float*)d_in[4];
  const float* w_proj = (const float*)d_in[5];
  const float* b_proj = (const float*)d_in[6];
  const float *ws_[3], *bs_[3], *wm_[3], *bm_[3], *we_[3], *be_[3];
  for (int i = 0; i < 3; ++i) {
    ws_[i] = (const float*)d_in[7 + 6 * i];
    bs_[i] = (const float*)d_in[8 + 6 * i];
    wm_[i] = (const float*)d_in[9 + 6 * i];
    bm_[i] = (const float*)d_in[10 + 6 * i];
    we_[i] = (const float*)d_in[11 + 6 * i];
    be_[i] = (const float*)d_in[12 + 6 * i];
  }
  float* out = (float*)d_out;

  // ---- workspace ----
  char* base = (char*)d_ws;
  size_t o = 0;
  int* ctrl = (int*)(base + o); o += 256;
  u32* mb1 = (u32*)(base + o); o += MBW * 4;
  u32* mb2 = (u32*)(base + o); o += MBW * 4;
  int* deg = (int*)(base + o); o += (size_t)N_NODES * 4;
  size_t zero_bytes = o;  // ctrl + masks + deg zeroed each call
  int* offn = (int*)(base + o); o += (size_t)N_NODES * 4;
  int* cur = (int*)(base + o); o += (size_t)N_NODES * 4;
  int2* csr_se = (int2*)(base + o); o += (size_t)CAP_SLOTS * 8;
  int* csr_dst = (int*)(base + o); o += (size_t)CAP_SLOTS * 4;
  o = (o + 15) & ~(size_t)15;
  int4* E2 = (int4*)(base + o); o += (size_t)CAP_E2 * 16;
  int4* E3 = (int4*)(base + o); o += (size_t)CAP_E3 * 16;
  int* L1 = (int*)(base + o); o += (size_t)CAP_L1 * 4;
  int* L2 = (int*)(base + o); o += (size_t)CAP_L2 * 4;
  float* degf = (float*)(base + o); o += (size_t)CAP_L1 * 4;
  o = (o + 15) & ~(size_t)15;
  u32* w1p = (u32*)(base + o); o += (size_t)NPK * 4;
  u32* e1p = (u32*)(base + o); o += (size_t)NPK * 4;
  u32* w2p = (u32*)(base + o); o += (size_t)NPK * 4;
  u32* e2p = (u32*)(base + o); o += (size_t)NPK * 4;
  u32* w3p = (u32*)(base + o); o += (size_t)NPK * 4;
  o = (o + 511) & ~(size_t)511;
  u16* A_n = (u16*)(base + o); o += (size_t)CAP_L1 * 384 * 2;   // 12.6 MB
  u16* A_e = (u16*)(base + o); o += (size_t)CAP_E2 * 384 * 2;   // 12.6 MB
  float* x1 = (float*)(base + o); o += (size_t)N_NODES * D * 4; // 51 MB
  float* x2 = (float*)(base + o); o += (size_t)N_NODES * D * 4; // 51 MB
  u16* ea = (u16*)(base + o); o += (size_t)CAP_SLOTS * D * 2;   // 16 MB

  hipMemsetAsync(d_ws, 0, zero_bytes, stream);

  dim3 B(256);
  const int EG4 = (N_EDGES / 4 + 255) / 256;  // 586
  const int AG = (N_NODES + 1023) / 1024;     // 98

  // cone + CSR
  k_scan3<<<EG4, B, 0, stream>>>(src4, dst4, mb1, mb2);
  k_scan2<<<EG4, B, 0, stream>>>(src4, dst4, mb2, mb1);
  k_scan1<<<EG4, B, 0, stream>>>(dst4, mb1, deg);
  k_alloc<<<AG, dim3(1024), 0, stream>>>(mb1, mb2, deg, offn, cur, L1, L2, ctrl);
  k_scatter<<<EG4, B, 0, stream>>>(src4, dst4, mb1, cur, csr_se, csr_dst, ctrl);
  k_aux<<<512, B, 0, stream>>>(csr_se, csr_dst, mb2, E2, E3, ctrl,
                               ws_[0], wm_[0], we_[0],
                               ws_[1], wm_[1], we_[1],
                               ws_[2], wm_[2],
                               w1p, e1p, w2p, e2p, w3p);

  GJob jn, je, jz;
  // ---- stage 1 ----
  k_gather<<<1280, B, 0, stream>>>(tok, emb, nullptr, attr, w_proj, b_proj, ea,
                                   csr_se, offn, cur, L1, E2, ctrl,
                                   C_L1, CAP_L1, C_E2, CAP_E2, 640, A_n, A_e, degf);
  jn = {A_n, w1p, bs_[0], bm_[0], degf, L1, nullptr, x1, nullptr, C_L1, CAP_L1, 1};
  je = {A_e, e1p, be_[0], nullptr, nullptr, nullptr, E2, nullptr, ea, C_E2, CAP_E2, 1};
  k_gemm_b<<<448, B, 0, stream>>>(jn, je, 2, ctrl);

  // ---- stage 2 ----
  k_gather<<<192, B, 0, stream>>>(nullptr, nullptr, x1, nullptr, nullptr, nullptr, ea,
                                  csr_se, offn, cur, L2, E3, ctrl,
                                  C_L2, CAP_L2, C_E3, CAP_E3, 96, A_n, A_e, degf);
  jn = {A_n, w2p, bs_[1], bm_[1], degf, L2, nullptr, x2, nullptr, C_L2, CAP_L2, 1};
  je = {A_e, e2p, be_[1], nullptr, nullptr, nullptr, E3, nullptr, ea, C_E3, CAP_E3, 1};
  k_gemm_b<<<128, B, 0, stream>>>(jn, je, 2, ctrl);

  // ---- stage 3: masters only, no relu ----
  k_gather<<<16, B, 0, stream>>>(nullptr, nullptr, x2, nullptr, nullptr, nullptr, ea,
                                 csr_se, offn, cur, nullptr, nullptr, ctrl,
                                 -1, NGRAPH, -1, 0, 16, A_n, A_e, degf);
  jn = {A_n, w3p, bs_[2], bm_[2], degf, nullptr, nullptr, out, nullptr, -1, NGRAPH, 0};
  jz = {};
  k_gemm_b<<<16, B, 0, stream>>>(jn, jz, 1, ctrl);
}

// Round 10
// 132.640 us; speedup vs baseline: 2.6569x; 1.0010x over previous
//
#include <hip/hip_runtime.h>

typedef unsigned short u16;
typedef unsigned int u32;
typedef unsigned long long u64;

#define N_NODES 100000
#define N_EDGES 600000
#define D 128
#define NPG 1000
#define NGRAPH 100
#define MBW 3136          // mask words (padded) >= ceil(100000/32)

#define CAP_SLOTS 65536   // CSR slots (expected ~29.4k)
#define CAP_L1    16384   // S1 nodes (expected ~4.9k)
#define CAP_L2    4096    // S2 nodes (expected ~700)
#define CAP_E2    16384   // edges into S2 (expected ~4.2k)
#define CAP_E3    4096    // edges into masters (expected ~600)

#define C_SLOT 0
#define C_L1   1
#define C_L2   2
#define C_E2   3
#define C_E3   4
#define C64    8          // int-index of packed u64 alloc counter (byte 32, 8-aligned)

#define NPK (192 * 128)   // packed W elements (u32) per job: 24576
#define ZWORDS (64 + 2 * MBW)   // ctrl (256B) + mb1 + mb2, in u32 words

__device__ __forceinline__ float bf2f(u16 u) {
  return __uint_as_float(((u32)u) << 16);
}
__device__ __forceinline__ u16 f2bf(float f) {
  u32 u = __float_as_uint(f);
  u32 r = (u + 0x7FFFu + ((u >> 16) & 1u)) >> 16;  // RNE
  return (u16)r;
}
__device__ __forceinline__ u32 packbf2(float a, float b) {
  return (u32)f2bf(a) | ((u32)f2bf(b) << 16);
}
__device__ __forceinline__ void fma4(float4& acc, float a, const float4 w) {
  acc.x = fmaf(a, w.x, acc.x);
  acc.y = fmaf(a, w.y, acc.y);
  acc.z = fmaf(a, w.z, acc.z);
  acc.w = fmaf(a, w.w, acc.w);
}
__device__ __forceinline__ float4 bf4(uint2 u) {
  return make_float4(bf2f((u16)(u.x & 0xFFFFu)), bf2f((u16)(u.x >> 16)),
                     bf2f((u16)(u.y & 0xFFFFu)), bf2f((u16)(u.y >> 16)));
}
__device__ __forceinline__ void add4(float4& a, const float4 b) {
  a.x += b.x; a.y += b.y; a.z += b.z; a.w += b.w;
}
__device__ __forceinline__ float4 shfl4(float4 v, int lane) {
  return make_float4(__shfl(v.x, lane, 32), __shfl(v.y, lane, 32),
                     __shfl(v.z, lane, 32), __shfl(v.w, lane, 32));
}
__device__ __forceinline__ int mbit(const u32* __restrict__ mb, int n) {
  return (mb[n >> 5] >> (n & 31)) & 1u;
}
__device__ __forceinline__ void mset(u32* __restrict__ mb, int n) {
  atomicOr(&mb[n >> 5], 1u << (n & 31));
}

// zero ctrl + masks (25.3 KB) — replaces the pathologically slow runtime fill
__global__ __launch_bounds__(256) void k_zero(u32* __restrict__ p) {
  int t = blockIdx.x * 256 + threadIdx.x;
  if (t < ZWORDS) p[t] = 0;
}

// ---------------- cone construction ----------------

__global__ __launch_bounds__(256) void k_scan3(const int4* __restrict__ src4,
                                               const int4* __restrict__ dst4,
                                               u32* __restrict__ mb1,
                                               u32* __restrict__ mb2,
                                               int* __restrict__ deg) {
  int i = blockIdx.x * 256 + threadIdx.x;
  if (i < N_NODES) deg[i] = 0;   // fold deg-zeroing here (scan1 writes it later)
  if (blockIdx.x == 0 && threadIdx.x < NGRAPH) {
    mset(mb2, threadIdx.x * NPG);
    mset(mb1, threadIdx.x * NPG);
  }
  if (i >= N_EDGES / 4) return;
  int4 d = dst4[i], s = src4[i];
  if (d.x % NPG == 0) { mset(mb2, s.x); mset(mb1, s.x); }
  if (d.y % NPG == 0) { mset(mb2, s.y); mset(mb1, s.y); }
  if (d.z % NPG == 0) { mset(mb2, s.z); mset(mb1, s.z); }
  if (d.w % NPG == 0) { mset(mb2, s.w); mset(mb1, s.w); }
}

__global__ __launch_bounds__(256) void k_scan2(const int4* __restrict__ src4,
                                               const int4* __restrict__ dst4,
                                               const u32* __restrict__ mb2,
                                               u32* __restrict__ mb1) {
  int i = blockIdx.x * 256 + threadIdx.x;
  if (i >= N_EDGES / 4) return;
  int4 d = dst4[i], s = src4[i];
  if (mbit(mb2, d.x)) mset(mb1, s.x);
  if (mbit(mb2, d.y)) mset(mb1, s.y);
  if (mbit(mb2, d.z)) mset(mb1, s.z);
  if (mbit(mb2, d.w)) mset(mb1, s.w);
}

__global__ __launch_bounds__(256) void k_scan1(const int4* __restrict__ dst4,
                                               const u32* __restrict__ mb1,
                                               int* __restrict__ deg) {
  int i = blockIdx.x * 256 + threadIdx.x;
  if (i >= N_EDGES / 4) return;
  int4 d = dst4[i];
  if (mbit(mb1, d.x)) atomicAdd(&deg[d.x], 1);
  if (mbit(mb1, d.y)) atomicAdd(&deg[d.y], 1);
  if (mbit(mb1, d.z)) atomicAdd(&deg[d.z], 1);
  if (mbit(mb1, d.w)) atomicAdd(&deg[d.w], 1);
}

// CSR allocation: block-wide scan, ONE packed-u64 atomic per block (98 total).
// Packed fields: slot [0,24) | L1 [24,44) | L2 [44,64).
__global__ __launch_bounds__(1024) void k_alloc(const u32* __restrict__ mb1,
                                                const u32* __restrict__ mb2,
                                                const int* __restrict__ deg,
                                                int* __restrict__ offn,
                                                int* __restrict__ cur,
                                                int* __restrict__ L1,
                                                int* __restrict__ L2,
                                                int* __restrict__ ctrl) {
  __shared__ int wsum[16], wcnt1[16], wcnt2[16];
  __shared__ int bbase[3];
  int tid = threadIdx.x, lane = tid & 63, wid = tid >> 6;
  int t = blockIdx.x * 1024 + tid;
  bool inb = t < N_NODES;
  bool mk1 = inb && mbit(mb1, t);
  bool mk2 = inb && mbit(mb2, t);

  int v = mk1 ? deg[t] : 0;
  int incl = v;
#pragma unroll
  for (int o = 1; o < 64; o <<= 1) {
    int u = __shfl_up(incl, o, 64);
    if (lane >= o) incl += u;
  }
  u64 bal1 = __ballot(mk1);
  u64 bal2 = __ballot(mk2);
  if (lane == 63) {
    wsum[wid] = incl;
    wcnt1[wid] = __popcll(bal1);
    wcnt2[wid] = __popcll(bal2);
  }
  __syncthreads();
  if (wid == 0 && lane < 16) {
    int s0 = wsum[lane], c1 = wcnt1[lane], c2 = wcnt2[lane];
    int si = s0, c1i = c1, c2i = c2;
#pragma unroll
    for (int o = 1; o < 16; o <<= 1) {
      int a = __shfl_up(si, o, 64);
      int b = __shfl_up(c1i, o, 64);
      int c = __shfl_up(c2i, o, 64);
      if (lane >= o) { si += a; c1i += b; c2i += c; }
    }
    if (lane == 15) {
      u64 pk = (u64)si | ((u64)c1i << 24) | ((u64)c2i << 44);
      u64 old = atomicAdd((u64*)(ctrl + C64), pk);
      bbase[0] = (int)(old & 0xFFFFFF);
      bbase[1] = (int)((old >> 24) & 0xFFFFF);
      bbase[2] = (int)(old >> 44);
    }
    wsum[lane] = si - s0;   // exclusive wave bases
    wcnt1[lane] = c1i - c1;
    wcnt2[lane] = c2i - c2;
  }
  __syncthreads();
  if (mk1) {
    int myoff = bbase[0] + wsum[wid] + incl - v;
    offn[t] = myoff;
    cur[t] = myoff;
    int pos1 = bbase[1] + wcnt1[wid] + __popcll(bal1 & ((1ull << lane) - 1ull));
    if (pos1 < CAP_L1) L1[pos1] = t;
  }
  if (mk2) {
    int pos2 = bbase[2] + wcnt2[wid] + __popcll(bal2 & ((1ull << lane) - 1ull));
    if (pos2 < CAP_L2) L2[pos2] = t;
  }
}

// scatter edges into CSR (distributed cur atomics); block 0 unpacks alloc totals
__global__ __launch_bounds__(256) void k_scatter(const int4* __restrict__ src4,
                                                 const int4* __restrict__ dst4,
                                                 const u32* __restrict__ mb1,
                                                 int* __restrict__ cur,
                                                 int2* __restrict__ csr_se,
                                                 int* __restrict__ csr_dst,
                                                 int* __restrict__ ctrl) {
  if (blockIdx.x == 0 && threadIdx.x == 0) {
    u64 pk = *(const u64*)(ctrl + C64);
    ctrl[C_SLOT] = (int)(pk & 0xFFFFFF);
    ctrl[C_L1] = (int)((pk >> 24) & 0xFFFFF);
    ctrl[C_L2] = (int)(pk >> 44);
  }
  int i = blockIdx.x * 256 + threadIdx.x;
  if (i >= N_EDGES / 4) return;
  int4 dv = dst4[i], sv = src4[i];
  int ds[4] = {dv.x, dv.y, dv.z, dv.w};
  int ss[4] = {sv.x, sv.y, sv.z, sv.w};
#pragma unroll
  for (int j = 0; j < 4; ++j) {
    int d = ds[j];
    if (!mbit(mb1, d)) continue;
    int p = atomicAdd(&cur[d], 1);
    if (p < CAP_SLOTS) {
      csr_se[p] = make_int2(ss[j], i * 4 + j);
      csr_dst[p] = d;
    }
  }
}

// merged: blocks [0,480): pack 5 weight buffers to bf16 K-pairs;
//         blocks [480,512): build E2/E3 lists
__global__ __launch_bounds__(256) void k_aux(const int2* __restrict__ csr_se,
                                             const int* __restrict__ csr_dst,
                                             const u32* __restrict__ mb2,
                                             int4* __restrict__ E2,
                                             int4* __restrict__ E3,
                                             int* __restrict__ ctrl,
                                             const float* __restrict__ ws1, const float* __restrict__ wm1,
                                             const float* __restrict__ we1,
                                             const float* __restrict__ ws2, const float* __restrict__ wm2,
                                             const float* __restrict__ we2,
                                             const float* __restrict__ ws3, const float* __restrict__ wm3,
                                             u32* __restrict__ w1p, u32* __restrict__ e1p,
                                             u32* __restrict__ w2p, u32* __restrict__ e2p,
                                             u32* __restrict__ w3p) {
  if (blockIdx.x < 480) {  // 480*256 == 5*NPK
    int t = blockIdx.x * 256 + threadIdx.x;
    int buf = t / NPK, elem = t % NPK;
    int k2 = elem >> 7, c = elem & 127;
    int k0 = 2 * k2, k1 = 2 * k2 + 1;
    float a, b;
    u32* dst;
    if (buf == 0) {
      a = k0 < 128 ? ws1[k0 * 128 + c] : wm1[(k0 - 128) * 128 + c];
      b = k1 < 128 ? ws1[k1 * 128 + c] : wm1[(k1 - 128) * 128 + c];
      dst = w1p;
    } else if (buf == 1) {
      a = we1[k0 * 128 + c]; b = we1[k1 * 128 + c]; dst = e1p;
    } else if (buf == 2) {
      a = k0 < 128 ? ws2[k0 * 128 + c] : wm2[(k0 - 128) * 128 + c];
      b = k1 < 128 ? ws2[k1 * 128 + c] : wm2[(k1 - 128) * 128 + c];
      dst = w2p;
    } else if (buf == 3) {
      a = we2[k0 * 128 + c]; b = we2[k1 * 128 + c]; dst = e2p;
    } else {
      a = k0 < 128 ? ws3[k0 * 128 + c] : wm3[(k0 - 128) * 128 + c];
      b = k1 < 128 ? ws3[k1 * 128 + c] : wm3[(k1 - 128) * 128 + c];
      dst = w3p;
    }
    dst[elem] = packbf2(a, b);
    return;
  }
  int lb = blockIdx.x - 480;  // 32 list blocks
  int ns = ctrl[C_SLOT];
  if (ns > CAP_SLOTS) ns = CAP_SLOTS;
  int lane = threadIdx.x & 63;
  int total = (ns + 255) & ~255;
  for (int p = lb * 256 + threadIdx.x; p < total; p += 32 * 256) {
    bool inb = p < ns;
    int d = inb ? csr_dst[p] : 0;
    bool e2 = inb && mbit(mb2, d);
    bool e3 = inb && (d % NPG == 0);
    int2 se = (e2 || e3) ? csr_se[p] : make_int2(0, 0);
    u64 bal = __ballot(e2);
    if (bal) {
      int base = 0;
      if (lane == 0) base = atomicAdd(&ctrl[C_E2], __popcll(bal));
      base = __shfl(base, 0, 64);
      int pos = __popcll(bal & ((1ull << lane) - 1ull));
      if (e2 && base + pos < CAP_E2) E2[base + pos] = make_int4(p, se.x, d, se.y);
    }
    u64 bal3 = __ballot(e3);
    if (bal3) {
      int base = 0;
      if (lane == 0) base = atomicAdd(&ctrl[C_E3], __popcll(bal3));
      base = __shfl(base, 0, 64);
      int pos = __popcll(bal3 & ((1ull << lane) - 1ull));
      if (e3 && base + pos < CAP_E3) E3[base + pos] = make_int4(p, se.x, d, se.y);
    }
  }
}

// ---------------- merged gather: blocks [0,split) node rows, [split,..) edge rows

__device__ __forceinline__ void store_bf16_seg(u16* Arow, int seg, int q, float4 v) {
  ((uint2*)Arow)[seg * 32 + q] = make_uint2(packbf2(v.x, v.y), packbf2(v.z, v.w));
}

__global__ __launch_bounds__(256) void k_gather(const int* __restrict__ tok,
                                                const float* __restrict__ emb,
                                                const float* __restrict__ xin,
                                                const float* __restrict__ attr,
                                                const float* __restrict__ wproj,
                                                const float* __restrict__ bproj,
                                                const u16* __restrict__ ea,
                                                const int2* __restrict__ csr_se,
                                                const int* __restrict__ offn,
                                                const int* __restrict__ cur,
                                                const int* __restrict__ L,
                                                const int4* __restrict__ EL,
                                                const int* __restrict__ ctrl,
                                                int slotN, int capN, int slotE, int capE,
                                                int split,
                                                u16* __restrict__ An,
                                                u16* __restrict__ Ae,
                                                float* __restrict__ degf) {
  int sub = threadIdx.x >> 5, q = threadIdx.x & 31;
  if (blockIdx.x < split) {
    // ---- node gather ----
    int n_ = L ? ctrl[slotN] : NGRAPH;
    if (n_ > capN) n_ = capN;
    for (int i = blockIdx.x * 8 + sub; i < n_; i += split * 8) {
      int n = L ? L[i] : i * NPG;
      int o = offn[n], end = cur[n];
      float dgf = (float)(end - o);
      float4 sx = make_float4(0.f, 0.f, 0.f, 0.f);
      float4 se = make_float4(0.f, 0.f, 0.f, 0.f);
      float4 xn;
      if (tok) {
        float4 sa = make_float4(0.f, 0.f, 0.f, 0.f);
        for (int p = o; p < end; ++p) {
          int2 se2 = csr_se[p];
          add4(sx, ((const float4*)(emb + (size_t)tok[se2.x] * D))[q]);
          add4(sa, ((const float4*)(attr + (size_t)se2.y * 16))[q & 3]);
        }
        float4 bp = ((const float4*)bproj)[q];
        se = make_float4(bp.x * dgf, bp.y * dgf, bp.z * dgf, bp.w * dgf);
        const float4* wp = (const float4*)wproj;
#pragma unroll
        for (int k4 = 0; k4 < 4; ++k4) {
          float4 xv = shfl4(sa, k4);
          fma4(se, xv.x, wp[(k4 * 4 + 0) * 32 + q]);
          fma4(se, xv.y, wp[(k4 * 4 + 1) * 32 + q]);
          fma4(se, xv.z, wp[(k4 * 4 + 2) * 32 + q]);
          fma4(se, xv.w, wp[(k4 * 4 + 3) * 32 + q]);
        }
        xn = ((const float4*)(emb + (size_t)tok[n] * D))[q];
      } else {
        for (int p = o; p < end; ++p) {
          int s = csr_se[p].x;
          add4(sx, ((const float4*)(xin + (size_t)s * D))[q]);
          add4(se, bf4(((const uint2*)(ea + (size_t)p * D))[q]));
        }
        xn = ((const float4*)(xin + (size_t)n * D))[q];
      }
      u16* Ar = An + (size_t)i * 384;
      store_bf16_seg(Ar, 0, q, xn);
      store_bf16_seg(Ar, 1, q, sx);
      store_bf16_seg(Ar, 2, q, se);
      if (q == 0) degf[i] = dgf;
    }
  } else {
    // ---- edge gather ----
    if (slotE < 0) return;
    int n_ = ctrl[slotE];
    if (n_ > capE) n_ = capE;
    int eb = gridDim.x - split;
    for (int i = (blockIdx.x - split) * 8 + sub; i < n_; i += eb * 8) {
      int4 t = EL[i];
      int p = t.x, s = t.y, d = t.z, e = t.w;
      float4 xd, xs, ev;
      if (tok) {
        xd = ((const float4*)(emb + (size_t)tok[d] * D))[q];
        xs = ((const float4*)(emb + (size_t)tok[s] * D))[q];
        float4 av = ((const float4*)(attr + (size_t)e * 16))[q & 3];
        ev = ((const float4*)bproj)[q];
        const float4* wp = (const float4*)wproj;
#pragma unroll
        for (int k4 = 0; k4 < 4; ++k4) {
          float4 xv = shfl4(av, k4);
          fma4(ev, xv.x, wp[(k4 * 4 + 0) * 32 + q]);
          fma4(ev, xv.y, wp[(k4 * 4 + 1) * 32 + q]);
          fma4(ev, xv.z, wp[(k4 * 4 + 2) * 32 + q]);
          fma4(ev, xv.w, wp[(k4 * 4 + 3) * 32 + q]);
        }
      } else {
        xd = ((const float4*)(xin + (size_t)d * D))[q];
        xs = ((const float4*)(xin + (size_t)s * D))[q];
        ev = bf4(((const uint2*)(ea + (size_t)p * D))[q]);
      }
      u16* Ar = Ae + (size_t)i * 384;
      store_bf16_seg(Ar, 0, q, xd);
      store_bf16_seg(Ar, 1, q, xs);
      store_bf16_seg(Ar, 2, q, ev);
    }
  }
}

// ---------------- W-resident GEMM (unchanged from R8) ----------------

struct GJob {
  const u16* A;
  const u32* W;        // packed bf16 K-pairs [192][128]
  const float* bias;
  const float* bm;     // null for edge jobs
  const float* degf;   // null for edge jobs
  const int* L;        // node list or null (row index direct)
  const int4* EL;      // edge list (bf16 out slot) or null
  float* outf;
  u16* outb;
  int slot;            // ctrl slot for M, or -1 -> NGRAPH
  int cap;
  int relu;
};

#define ASF(x) __uint_as_float(x)

__global__ __launch_bounds__(256) void k_gemm_b(GJob J0, GJob J1, int njobs,
                                                const int* __restrict__ ctrl) {
  __shared__ uint4 Wl4[3072];   // 48 KB: u32 layout [k2][64] for this col-half
  __shared__ uint4 Al4[768];    // 12 KB: 16 rows x 384 bf16
  const u32* Wlds = (const u32*)Wl4;
  int q = threadIdx.x & 63, wv = threadIdx.x >> 6;

  int job, half, lid, cnt;
  if (njobs == 2) {
    job = (blockIdx.x & 2) >> 1; half = blockIdx.x & 1;
    lid = blockIdx.x >> 2; cnt = gridDim.x >> 2;
  } else {
    job = 0; half = blockIdx.x & 1;
    lid = blockIdx.x >> 1; cnt = gridDim.x >> 1;
  }
  const GJob& J = job ? J1 : J0;
  int M = J.slot < 0 ? NGRAPH : ctrl[J.slot];
  if (M > J.cap) M = J.cap;
  int nt = (M + 15) >> 4;

#pragma unroll
  for (int u = 0; u < 12; ++u) {
    int idx = threadIdx.x + u * 256;        // 0..3071 uint4
    int k2 = idx >> 4, c4 = idx & 15;
    Wl4[idx] = ((const uint4*)J.W)[k2 * 32 + half * 16 + c4];
  }

  float bias = J.bias[half * 64 + q];
  float bmv = J.degf ? J.bm[half * 64 + q] : 0.f;

  for (int t = lid; t < nt; t += cnt) {
    __syncthreads();
#pragma unroll
    for (int u = 0; u < 3; ++u) {
      int idx = threadIdx.x + u * 256;      // 0..767 uint4
      int row = idx / 48, c8 = idx % 48;
      int gr = t * 16 + row;
      if (gr > M - 1) gr = M - 1;
      Al4[idx] = ((const uint4*)(J.A + (size_t)gr * 384))[c8];
    }
    __syncthreads();

    const uint2* A0 = (const uint2*)Al4 + (wv * 4 + 0) * 96;
    const uint2* A1 = (const uint2*)Al4 + (wv * 4 + 1) * 96;
    const uint2* A2 = (const uint2*)Al4 + (wv * 4 + 2) * 96;
    const uint2* A3 = (const uint2*)Al4 + (wv * 4 + 3) * 96;
    float acc0 = bias, acc1 = bias, acc2 = bias, acc3 = bias;
#pragma unroll 8
    for (int k4 = 0; k4 < 96; ++k4) {
      u32 wA = Wlds[(k4 * 2) * 64 + q];
      u32 wB = Wlds[(k4 * 2 + 1) * 64 + q];
      float wk0 = ASF(wA << 16), wk1 = ASF(wA & 0xffff0000u);
      float wk2 = ASF(wB << 16), wk3 = ASF(wB & 0xffff0000u);
      uint2 a;
      a = A0[k4];
      acc0 = fmaf(ASF(a.x << 16), wk0, acc0);
      acc0 = fmaf(ASF(a.x & 0xffff0000u), wk1, acc0);
      acc0 = fmaf(ASF(a.y << 16), wk2, acc0);
      acc0 = fmaf(ASF(a.y & 0xffff0000u), wk3, acc0);
      a = A1[k4];
      acc1 = fmaf(ASF(a.x << 16), wk0, acc1);
      acc1 = fmaf(ASF(a.x & 0xffff0000u), wk1, acc1);
      acc1 = fmaf(ASF(a.y << 16), wk2, acc1);
      acc1 = fmaf(ASF(a.y & 0xffff0000u), wk3, acc1);
      a = A2[k4];
      acc2 = fmaf(ASF(a.x << 16), wk0, acc2);
      acc2 = fmaf(ASF(a.x & 0xffff0000u), wk1, acc2);
      acc2 = fmaf(ASF(a.y << 16), wk2, acc2);
      acc2 = fmaf(ASF(a.y & 0xffff0000u), wk3, acc2);
      a = A3[k4];
      acc3 = fmaf(ASF(a.x << 16), wk0, acc3);
      acc3 = fmaf(ASF(a.x & 0xffff0000u), wk1, acc3);
      acc3 = fmaf(ASF(a.y << 16), wk2, acc3);
      acc3 = fmaf(ASF(a.y & 0xffff0000u), wk3, acc3);
    }

    float accs[4] = {acc0, acc1, acc2, acc3};
#pragma unroll
    for (int r = 0; r < 4; ++r) {
      int row = t * 16 + wv * 4 + r;
      if (row < M) {
        float a = accs[r];
        if (J.degf) a = fmaf(J.degf[row], bmv, a);
        if (J.relu) a = fmaxf(a, 0.f);
        if (J.outb) {
          int p = J.EL[row].x;
          J.outb[(size_t)p * D + half * 64 + q] = f2bf(a);
        } else {
          int idx = J.L ? J.L[row] : row;
          J.outf[(size_t)idx * D + half * 64 + q] = a;
        }
      }
    }
  }
}

extern "C" void kernel_launch(void* const* d_in, const int* in_sizes, int n_in,
                              void* d_out, int out_size, void* d_ws, size_t ws_size,
                              hipStream_t stream) {
  const int* tok = (const int*)d_in[0];
  const int* eidx = (const int*)d_in[1];
  const int4* src4 = (const int4*)eidx;
  const int4* dst4 = (const int4*)(eidx + N_EDGES);
  const float* attr = (const float*)d_in[2];
  const float* emb = (const float*)d_in[4];
  const float* w_proj = (const float*)d_in[5];
  const float* b_proj = (const float*)d_in[6];
  const float *ws_[3], *bs_[3], *wm_[3], *bm_[3], *we_[3], *be_[3];
  for (int i = 0; i < 3; ++i) {
    ws_[i] = (const float*)d_in[7 + 6 * i];
    bs_[i] = (const float*)d_in[8 + 6 * i];
    wm_[i] = (const float*)d_in[9 + 6 * i];
    bm_[i] = (const float*)d_in[10 + 6 * i];
    we_[i] = (const float*)d_in[11 + 6 * i];
    be_[i] = (const float*)d_in[12 + 6 * i];
  }
  float* out = (float*)d_out;

  // ---- workspace ----
  char* base = (char*)d_ws;
  size_t o = 0;
  int* ctrl = (int*)(base + o); o += 256;
  u32* mb1 = (u32*)(base + o); o += MBW * 4;
  u32* mb2 = (u32*)(base + o); o += MBW * 4;   // [ctrl|mb1|mb2] = k_zero range
  int* deg = (int*)(base + o); o += (size_t)N_NODES * 4;  // zeroed in k_scan3
  int* offn = (int*)(base + o); o += (size_t)N_NODES * 4;
  int* cur = (int*)(base + o); o += (size_t)N_NODES * 4;
  int2* csr_se = (int2*)(base + o); o += (size_t)CAP_SLOTS * 8;
  int* csr_dst = (int*)(base + o); o += (size_t)CAP_SLOTS * 4;
  o = (o + 15) & ~(size_t)15;
  int4* E2 = (int4*)(base + o); o += (size_t)CAP_E2 * 16;
  int4* E3 = (int4*)(base + o); o += (size_t)CAP_E3 * 16;
  int* L1 = (int*)(base + o); o += (size_t)CAP_L1 * 4;
  int* L2 = (int*)(base + o); o += (size_t)CAP_L2 * 4;
  float* degf = (float*)(base + o); o += (size_t)CAP_L1 * 4;
  o = (o + 15) & ~(size_t)15;
  u32* w1p = (u32*)(base + o); o += (size_t)NPK * 4;
  u32* e1p = (u32*)(base + o); o += (size_t)NPK * 4;
  u32* w2p = (u32*)(base + o); o += (size_t)NPK * 4;
  u32* e2p = (u32*)(base + o); o += (size_t)NPK * 4;
  u32* w3p = (u32*)(base + o); o += (size_t)NPK * 4;
  o = (o + 511) & ~(size_t)511;
  u16* A_n = (u16*)(base + o); o += (size_t)CAP_L1 * 384 * 2;   // 12.6 MB
  u16* A_e = (u16*)(base + o); o += (size_t)CAP_E2 * 384 * 2;   // 12.6 MB
  float* x1 = (float*)(base + o); o += (size_t)N_NODES * D * 4; // 51 MB
  float* x2 = (float*)(base + o); o += (size_t)N_NODES * D * 4; // 51 MB
  u16* ea = (u16*)(base + o); o += (size_t)CAP_SLOTS * D * 2;   // 16 MB

  dim3 B(256);
  const int EG4 = (N_EDGES / 4 + 255) / 256;  // 586
  const int AG = (N_NODES + 1023) / 1024;     // 98
  const int ZG = (ZWORDS + 255) / 256;        // 25

  // zero ctrl+masks ourselves (runtime fill kernel was 40 us for 425 KB)
  k_zero<<<ZG, B, 0, stream>>>((u32*)d_ws);

  // cone + CSR
  k_scan3<<<EG4, B, 0, stream>>>(src4, dst4, mb1, mb2, deg);
  k_scan2<<<EG4, B, 0, stream>>>(src4, dst4, mb2, mb1);
  k_scan1<<<EG4, B, 0, stream>>>(dst4, mb1, deg);
  k_alloc<<<AG, dim3(1024), 0, stream>>>(mb1, mb2, deg, offn, cur, L1, L2, ctrl);
  k_scatter<<<EG4, B, 0, stream>>>(src4, dst4, mb1, cur, csr_se, csr_dst, ctrl);
  k_aux<<<512, B, 0, stream>>>(csr_se, csr_dst, mb2, E2, E3, ctrl,
                               ws_[0], wm_[0], we_[0],
                               ws_[1], wm_[1], we_[1],
                               ws_[2], wm_[2],
                               w1p, e1p, w2p, e2p, w3p);

  GJob jn, je, jz;
  // ---- stage 1 ----
  k_gather<<<1280, B, 0, stream>>>(tok, emb, nullptr, attr, w_proj, b_proj, ea,
                                   csr_se, offn, cur, L1, E2, ctrl,
                                   C_L1, CAP_L1, C_E2, CAP_E2, 640, A_n, A_e, degf);
  jn = {A_n, w1p, bs_[0], bm_[0], degf, L1, nullptr, x1, nullptr, C_L1, CAP_L1, 1};
  je = {A_e, e1p, be_[0], nullptr, nullptr, nullptr, E2, nullptr, ea, C_E2, CAP_E2, 1};
  k_gemm_b<<<448, B, 0, stream>>>(jn, je, 2, ctrl);

  // ---- stage 2 ----
  k_gather<<<192, B, 0, stream>>>(nullptr, nullptr, x1, nullptr, nullptr, nullptr, ea,
                                  csr_se, offn, cur, L2, E3, ctrl,
                                  C_L2, CAP_L2, C_E3, CAP_E3, 96, A_n, A_e, degf);
  jn = {A_n, w2p, bs_[1], bm_[1], degf, L2, nullptr, x2, nullptr, C_L2, CAP_L2, 1};
  je = {A_e, e2p, be_[1], nullptr, nullptr, nullptr, E3, nullptr, ea, C_E3, CAP_E3, 1};
  k_gemm_b<<<128, B, 0, stream>>>(jn, je, 2, ctrl);

  // ---- stage 3: masters only, no relu ----
  k_gather<<<16, B, 0, stream>>>(nullptr, nullptr, x2, nullptr, nullptr, nullptr, ea,
                                 csr_se, offn, cur, nullptr, nullptr, ctrl,
                                 -1, NGRAPH, -1, 0, 16, A_n, A_e, degf);
  jn = {A_n, w3p, bs_[2], bm_[2], degf, nullptr, nullptr, out, nullptr, -1, NGRAPH, 0};
  jz = {};
  k_gemm_b<<<16, B, 0, stream>>>(jn, jz, 1, ctrl);
}